// Round 2
// baseline (10655.698 us; speedup 1.0000x reference)
//
#include <hip/hip_runtime.h>
#include <math.h>

#define NN 100000
#define NE 1000000
#define H 64

static __device__ __forceinline__ float relu_(float x){ return fmaxf(x, 0.0f); }

// ---------------- encoder: h = relu(relu(x@w1+b1)@w2+b2), x:[N,5] ----------------
__global__ __launch_bounds__(256, 2) void enc_kernel(
    const float* __restrict__ x,
    const float* __restrict__ w1, const float* __restrict__ b1,
    const float* __restrict__ w2, const float* __restrict__ b2,
    float* __restrict__ h)
{
  int v = blockIdx.x*256 + threadIdx.x;
  if (v >= NN) return;
  float in0[5];
  #pragma unroll
  for (int k=0;k<5;k++) in0[k] = x[v*5+k];
  float hid[H];
  #pragma unroll
  for (int j=0;j<H;j++) hid[j] = b1[j];
  #pragma unroll
  for (int k=0;k<5;k++){
    #pragma unroll
    for (int j=0;j<H;j++) hid[j] = fmaf(in0[k], w1[k*H+j], hid[j]);
  }
  float o[H];
  #pragma unroll
  for (int j=0;j<H;j++) o[j] = b2[j];
  #pragma unroll
  for (int k=0;k<H;k++){
    float hk = relu_(hid[k]);
    #pragma unroll
    for (int j=0;j<H;j++) o[j] = fmaf(hk, w2[k*H+j], o[j]);
  }
  float4* hw = (float4*)(h + (size_t)v*H);
  #pragma unroll
  for (int j4=0;j4<H/4;j4++){
    float4 t;
    t.x = relu_(o[4*j4+0]); t.y = relu_(o[4*j4+1]);
    t.z = relu_(o[4*j4+2]); t.w = relu_(o[4*j4+3]);
    hw[j4] = t;
  }
}

// ---------------- in-degree counts ----------------
__global__ __launch_bounds__(256) void deg_kernel(const int* __restrict__ dst,
                                                  int* __restrict__ counts)
{
  int e = blockIdx.x*256 + threadIdx.x;
  if (e < NE) atomicAdd(&counts[dst[e]], 1);
}

// ---------------- exclusive scan of counts -> row_start[NN+1] (single block) ----------------
__global__ __launch_bounds__(1024) void scan_kernel(const int* __restrict__ counts,
                                                    int* __restrict__ row_start)
{
  __shared__ int buf[1024];
  __shared__ int carry_s;
  if (threadIdx.x == 0) carry_s = 0;
  __syncthreads();
  for (int base = 0; base < NN; base += 1024){
    int i = base + (int)threadIdx.x;
    int v = (i < NN) ? counts[i] : 0;
    buf[threadIdx.x] = v;
    __syncthreads();
    #pragma unroll
    for (int off = 1; off < 1024; off <<= 1){
      int t = (threadIdx.x >= (unsigned)off) ? buf[threadIdx.x - off] : 0;
      __syncthreads();
      buf[threadIdx.x] += t;
      __syncthreads();
    }
    int incl = buf[threadIdx.x];
    int carry = carry_s;
    if (i < NN) row_start[i] = carry + incl - v;
    __syncthreads();
    if (threadIdx.x == 1023) carry_s = carry + buf[1023];
    __syncthreads();
  }
  if (threadIdx.x == 0) row_start[NN] = carry_s;
}

// ---------------- fill dst-sorted edge order ----------------
__global__ __launch_bounds__(256) void fill_order_kernel(
    const int* __restrict__ dst, const int* __restrict__ row_start,
    int* __restrict__ cursor, int* __restrict__ order)
{
  int e = blockIdx.x*256 + threadIdx.x;
  if (e >= NE) return;
  int d = dst[e];
  int p = row_start[d] + atomicAdd(&cursor[d], 1);
  order[p] = e;
}

// ---------------- per-edge message MLP, write at sorted slot (no atomics) ----------------
__global__ __launch_bounds__(256, 2) void msg_kernel2(
    const float* __restrict__ h,
    const int* __restrict__ order,
    const int* __restrict__ src, const int* __restrict__ dst,
    const float* __restrict__ w1, const float* __restrict__ b1,
    const float* __restrict__ w2, const float* __restrict__ b2,
    float* __restrict__ m)
{
  int p = blockIdx.x*256 + threadIdx.x;
  if (p >= NE) return;
  int e = order[p];
  int s = src[e], d = dst[e];
  const float4* hs = (const float4*)(h + (size_t)s*H);
  const float4* hd = (const float4*)(h + (size_t)d*H);

  float hid[H];
  #pragma unroll
  for (int j=0;j<H;j++) hid[j] = b1[j];

  #pragma unroll 4
  for (int k4=0;k4<16;k4++){
    float4 a = hs[k4];
    const float* wr = w1 + (size_t)(4*k4)*H;
    #pragma unroll
    for (int j=0;j<H;j++) hid[j] = fmaf(a.x, wr[j], hid[j]);
    #pragma unroll
    for (int j=0;j<H;j++) hid[j] = fmaf(a.y, wr[H+j], hid[j]);
    #pragma unroll
    for (int j=0;j<H;j++) hid[j] = fmaf(a.z, wr[2*H+j], hid[j]);
    #pragma unroll
    for (int j=0;j<H;j++) hid[j] = fmaf(a.w, wr[3*H+j], hid[j]);
  }
  #pragma unroll 4
  for (int k4=0;k4<16;k4++){
    float4 a = hd[k4];
    const float* wr = w1 + (size_t)(64 + 4*k4)*H;
    #pragma unroll
    for (int j=0;j<H;j++) hid[j] = fmaf(a.x, wr[j], hid[j]);
    #pragma unroll
    for (int j=0;j<H;j++) hid[j] = fmaf(a.y, wr[H+j], hid[j]);
    #pragma unroll
    for (int j=0;j<H;j++) hid[j] = fmaf(a.z, wr[2*H+j], hid[j]);
    #pragma unroll
    for (int j=0;j<H;j++) hid[j] = fmaf(a.w, wr[3*H+j], hid[j]);
  }

  float o[H];
  #pragma unroll
  for (int j=0;j<H;j++) o[j] = b2[j];
  #pragma unroll
  for (int k=0;k<H;k++){
    float hk = relu_(hid[k]);
    #pragma unroll
    for (int j=0;j<H;j++) o[j] = fmaf(hk, w2[k*H+j], o[j]);
  }

  float4* mw = (float4*)(m + (size_t)p*H);
  #pragma unroll
  for (int j4=0;j4<H/4;j4++){
    float4 t;
    t.x = relu_(o[4*j4+0]); t.y = relu_(o[4*j4+1]);
    t.z = relu_(o[4*j4+2]); t.w = relu_(o[4*j4+3]);
    mw[j4] = t;
  }
}

// ---------------- wave-per-node aggregate: agg[v][j] = mean over sorted rows ----------------
__global__ __launch_bounds__(256) void agg_kernel(
    const float* __restrict__ m, const int* __restrict__ row_start,
    float* __restrict__ agg)
{
  int gw = (blockIdx.x*256 + (int)threadIdx.x) >> 6;   // one wave per node
  int lane = threadIdx.x & 63;
  if (gw >= NN) return;
  int b = row_start[gw];
  int cnt = row_start[gw+1] - b;
  float s = 0.0f;
  for (int p = b; p < b + cnt; p++)
    s += m[(size_t)p*H + lane];
  agg[(size_t)gw*H + lane] = s / fmaxf((float)cnt, 1.0f);
}

// ---------------- fallback: per-edge message MLP + atomic scatter ----------------
__global__ __launch_bounds__(256, 2) void msg_kernel_atomic(
    const float* __restrict__ h,
    const int* __restrict__ src, const int* __restrict__ dst,
    const float* __restrict__ w1, const float* __restrict__ b1,
    const float* __restrict__ w2, const float* __restrict__ b2,
    float* __restrict__ agg)
{
  int e = blockIdx.x*256 + threadIdx.x;
  if (e >= NE) return;
  int s = src[e], d = dst[e];
  const float4* hs = (const float4*)(h + (size_t)s*H);
  const float4* hd = (const float4*)(h + (size_t)d*H);

  float hid[H];
  #pragma unroll
  for (int j=0;j<H;j++) hid[j] = b1[j];
  #pragma unroll 4
  for (int k4=0;k4<16;k4++){
    float4 a = hs[k4];
    const float* wr = w1 + (size_t)(4*k4)*H;
    #pragma unroll
    for (int j=0;j<H;j++) hid[j] = fmaf(a.x, wr[j], hid[j]);
    #pragma unroll
    for (int j=0;j<H;j++) hid[j] = fmaf(a.y, wr[H+j], hid[j]);
    #pragma unroll
    for (int j=0;j<H;j++) hid[j] = fmaf(a.z, wr[2*H+j], hid[j]);
    #pragma unroll
    for (int j=0;j<H;j++) hid[j] = fmaf(a.w, wr[3*H+j], hid[j]);
  }
  #pragma unroll 4
  for (int k4=0;k4<16;k4++){
    float4 a = hd[k4];
    const float* wr = w1 + (size_t)(64 + 4*k4)*H;
    #pragma unroll
    for (int j=0;j<H;j++) hid[j] = fmaf(a.x, wr[j], hid[j]);
    #pragma unroll
    for (int j=0;j<H;j++) hid[j] = fmaf(a.y, wr[H+j], hid[j]);
    #pragma unroll
    for (int j=0;j<H;j++) hid[j] = fmaf(a.z, wr[2*H+j], hid[j]);
    #pragma unroll
    for (int j=0;j<H;j++) hid[j] = fmaf(a.w, wr[3*H+j], hid[j]);
  }
  float o[H];
  #pragma unroll
  for (int j=0;j<H;j++) o[j] = b2[j];
  #pragma unroll
  for (int k=0;k<H;k++){
    float hk = relu_(hid[k]);
    #pragma unroll
    for (int j=0;j<H;j++) o[j] = fmaf(hk, w2[k*H+j], o[j]);
  }
  float* arow = agg + (size_t)d*H;
  #pragma unroll
  for (int j=0;j<H;j++) atomicAdd(arow + j, relu_(o[j]));
}

// ---------------- divide agg by degree (fallback path only) ----------------
__global__ __launch_bounds__(256) void div_kernel(float* __restrict__ agg,
                                                  const int* __restrict__ counts)
{
  int i = blockIdx.x*256 + threadIdx.x;
  if (i >= NN*H/4) return;
  int v = i / (H/4);
  float invd = 1.0f / fmaxf((float)counts[v], 1.0f);
  float4* a = (float4*)agg + i;
  float4 t = *a;
  t.x *= invd; t.y *= invd; t.z *= invd; t.w *= invd;
  *a = t;
}

// ---------------- per-node update MLP (in-place on h); agg pre-divided ----------------
__global__ __launch_bounds__(256, 2) void upd_kernel(
    float* __restrict__ h, const float* __restrict__ agg,
    const float* __restrict__ w1, const float* __restrict__ b1,
    const float* __restrict__ w2, const float* __restrict__ b2)
{
  int v = blockIdx.x*256 + threadIdx.x;
  if (v >= NN) return;
  const float4* hv = (const float4*)(h + (size_t)v*H);
  const float4* av = (const float4*)(agg + (size_t)v*H);

  float hid[H];
  #pragma unroll
  for (int j=0;j<H;j++) hid[j] = b1[j];

  #pragma unroll 4
  for (int k4=0;k4<16;k4++){
    float4 a = hv[k4];
    const float* wr = w1 + (size_t)(4*k4)*H;
    #pragma unroll
    for (int j=0;j<H;j++) hid[j] = fmaf(a.x, wr[j], hid[j]);
    #pragma unroll
    for (int j=0;j<H;j++) hid[j] = fmaf(a.y, wr[H+j], hid[j]);
    #pragma unroll
    for (int j=0;j<H;j++) hid[j] = fmaf(a.z, wr[2*H+j], hid[j]);
    #pragma unroll
    for (int j=0;j<H;j++) hid[j] = fmaf(a.w, wr[3*H+j], hid[j]);
  }
  #pragma unroll 4
  for (int k4=0;k4<16;k4++){
    float4 a = av[k4];
    const float* wr = w1 + (size_t)(64 + 4*k4)*H;
    #pragma unroll
    for (int j=0;j<H;j++) hid[j] = fmaf(a.x, wr[j], hid[j]);
    #pragma unroll
    for (int j=0;j<H;j++) hid[j] = fmaf(a.y, wr[H+j], hid[j]);
    #pragma unroll
    for (int j=0;j<H;j++) hid[j] = fmaf(a.z, wr[2*H+j], hid[j]);
    #pragma unroll
    for (int j=0;j<H;j++) hid[j] = fmaf(a.w, wr[3*H+j], hid[j]);
  }

  float o[H];
  #pragma unroll
  for (int j=0;j<H;j++) o[j] = b2[j];
  #pragma unroll
  for (int k=0;k<H;k++){
    float hk = relu_(hid[k]);
    #pragma unroll
    for (int j=0;j<H;j++) o[j] = fmaf(hk, w2[k*H+j], o[j]);
  }

  float4* hw = (float4*)(h + (size_t)v*H);
  #pragma unroll
  for (int j4=0;j4<H/4;j4++){
    float4 t;
    t.x = relu_(o[4*j4+0]); t.y = relu_(o[4*j4+1]);
    t.z = relu_(o[4*j4+2]); t.w = relu_(o[4*j4+3]);
    hw[j4] = t;
  }
}

// ---------------- output head: 2*pi*sigmoid(relu(h@w1+b1)@w2+b2) ----------------
__global__ __launch_bounds__(256, 2) void out_kernel(
    const float* __restrict__ h,
    const float* __restrict__ w1, const float* __restrict__ b1,
    const float* __restrict__ w2, const float* __restrict__ b2,
    float* __restrict__ out)
{
  int v = blockIdx.x*256 + threadIdx.x;
  if (v >= NN) return;
  const float4* hv = (const float4*)(h + (size_t)v*H);

  float hid[H];
  #pragma unroll
  for (int j=0;j<H;j++) hid[j] = b1[j];
  #pragma unroll 4
  for (int k4=0;k4<16;k4++){
    float4 a = hv[k4];
    const float* wr = w1 + (size_t)(4*k4)*H;
    #pragma unroll
    for (int j=0;j<H;j++) hid[j] = fmaf(a.x, wr[j], hid[j]);
    #pragma unroll
    for (int j=0;j<H;j++) hid[j] = fmaf(a.y, wr[H+j], hid[j]);
    #pragma unroll
    for (int j=0;j<H;j++) hid[j] = fmaf(a.z, wr[2*H+j], hid[j]);
    #pragma unroll
    for (int j=0;j<H;j++) hid[j] = fmaf(a.w, wr[3*H+j], hid[j]);
  }

  float p[3];
  #pragma unroll
  for (int c=0;c<3;c++) p[c] = b2[c];
  #pragma unroll
  for (int k=0;k<H;k++){
    float hk = relu_(hid[k]);
    #pragma unroll
    for (int c=0;c<3;c++) p[c] = fmaf(hk, w2[k*3+c], p[c]);
  }
  #pragma unroll
  for (int c=0;c<3;c++)
    out[(size_t)v*3+c] = 6.283185307179586f / (1.0f + __expf(-p[c]));
}

extern "C" void kernel_launch(void* const* d_in, const int* in_sizes, int n_in,
                              void* d_out, int out_size, void* d_ws, size_t ws_size,
                              hipStream_t stream)
{
  const float* x      = (const float*)d_in[0];
  const int*   ei     = (const int*)  d_in[1];
  const float* enc_w1 = (const float*)d_in[2];
  const float* enc_b1 = (const float*)d_in[3];
  const float* enc_w2 = (const float*)d_in[4];
  const float* enc_b2 = (const float*)d_in[5];
  const float* msg_w1 = (const float*)d_in[6];
  const float* msg_b1 = (const float*)d_in[7];
  const float* msg_w2 = (const float*)d_in[8];
  const float* msg_b2 = (const float*)d_in[9];
  const float* upd_w1 = (const float*)d_in[10];
  const float* upd_b1 = (const float*)d_in[11];
  const float* upd_w2 = (const float*)d_in[12];
  const float* upd_b2 = (const float*)d_in[13];
  const float* out_w1 = (const float*)d_in[14];
  const float* out_b1 = (const float*)d_in[15];
  const float* out_w2 = (const float*)d_in[16];
  const float* out_b2 = (const float*)d_in[17];
  float* out = (float*)d_out;

  const int* srcp = ei;
  const int* dstp = ei + NE;

  // workspace layout
  char* wp = (char*)d_ws;
  float* h = (float*)wp;            wp += (size_t)NN*H*sizeof(float);
  float* agg = (float*)wp;          wp += (size_t)NN*H*sizeof(float);
  int* counts = (int*)wp;           wp += (size_t)NN*sizeof(int);
  int* row_start = (int*)wp;        wp += (size_t)(NN+1)*sizeof(int);
  int* cursor = (int*)wp;           wp += (size_t)NN*sizeof(int);
  int* order = (int*)wp;            wp += (size_t)NE*sizeof(int);
  float* m = (float*)wp;            wp += (size_t)NE*H*sizeof(float);
  size_t need = (size_t)(wp - (char*)d_ws);

  const int nodeBlocks = (NN + 255)/256;
  const int edgeBlocks = (NE + 255)/256;
  const int waveBlocks = (NN*64 + 255)/256;

  hipMemsetAsync(counts, 0, NN*sizeof(int), stream);
  enc_kernel<<<nodeBlocks, 256, 0, stream>>>(x, enc_w1, enc_b1, enc_w2, enc_b2, h);
  deg_kernel<<<edgeBlocks, 256, 0, stream>>>(dstp, counts);

  if (ws_size >= need) {
    // CSR path: no fp32 atomics anywhere
    hipMemsetAsync(cursor, 0, NN*sizeof(int), stream);
    scan_kernel<<<1, 1024, 0, stream>>>(counts, row_start);
    fill_order_kernel<<<edgeBlocks, 256, 0, stream>>>(dstp, row_start, cursor, order);

    for (int l=0; l<3; l++){
      msg_kernel2<<<edgeBlocks, 256, 0, stream>>>(h, order, srcp, dstp,
          msg_w1 + (size_t)l*128*H, msg_b1 + (size_t)l*H,
          msg_w2 + (size_t)l*H*H,   msg_b2 + (size_t)l*H, m);
      agg_kernel<<<waveBlocks, 256, 0, stream>>>(m, row_start, agg);
      upd_kernel<<<nodeBlocks, 256, 0, stream>>>(h, agg,
          upd_w1 + (size_t)l*128*H, upd_b1 + (size_t)l*H,
          upd_w2 + (size_t)l*H*H,   upd_b2 + (size_t)l*H);
    }
  } else {
    // fallback: atomic scatter path
    for (int l=0; l<3; l++){
      hipMemsetAsync(agg, 0, (size_t)NN*H*sizeof(float), stream);
      msg_kernel_atomic<<<edgeBlocks, 256, 0, stream>>>(h, srcp, dstp,
          msg_w1 + (size_t)l*128*H, msg_b1 + (size_t)l*H,
          msg_w2 + (size_t)l*H*H,   msg_b2 + (size_t)l*H, agg);
      div_kernel<<<(NN*H/4 + 255)/256, 256, 0, stream>>>(agg, counts);
      upd_kernel<<<nodeBlocks, 256, 0, stream>>>(h, agg,
          upd_w1 + (size_t)l*128*H, upd_b1 + (size_t)l*H,
          upd_w2 + (size_t)l*H*H,   upd_b2 + (size_t)l*H);
    }
  }

  out_kernel<<<nodeBlocks, 256, 0, stream>>>(h, out_w1, out_b1, out_w2, out_b2, out);
}

// Round 3
// 1664.270 us; speedup vs baseline: 6.4026x; 6.4026x over previous
//
#include <hip/hip_runtime.h>
#include <math.h>

#define NN 100000
#define NE 1000000
#define H 64
#define MBK 192      // msg_agg block size (3 waves)
#define SLOT 33      // LDS row stride (pad) in floats

static __device__ __forceinline__ float relu_(float x){ return fmaxf(x, 0.0f); }

static __device__ __forceinline__ float b2f_(unsigned short u){
  union { float f; unsigned int i; } v; v.i = ((unsigned int)u) << 16; return v.f;
}
static __device__ __forceinline__ unsigned short f2b_(float f){
  union { float f; unsigned int i; } v; v.f = f;
  unsigned int r = (v.i + 0x7FFFu + ((v.i >> 16) & 1u)) >> 16;
  return (unsigned short)r;
}

static __device__ __forceinline__ void fma32(float* o, float a, const float* wr){
  #pragma unroll
  for (int j=0;j<32;j++) o[j] = fmaf(a, wr[j], o[j]);
}

// ---------------- encoder stage A: t = relu(x@w1+b1), x:[N,5] ----------------
__global__ __launch_bounds__(256) void enc_a_kernel(
    const float* __restrict__ x,
    const float* __restrict__ w1, const float* __restrict__ b1,
    float* __restrict__ t)
{
  int v = blockIdx.x*256 + threadIdx.x;
  if (v >= NN) return;
  float in0[5];
  #pragma unroll
  for (int k=0;k<5;k++) in0[k] = x[(size_t)v*5 + k];
  #pragma unroll 1
  for (int half=0; half<2; half++){
    float o[32];
    #pragma unroll
    for (int j=0;j<32;j++) o[j] = b1[half*32 + j];
    #pragma unroll
    for (int k=0;k<5;k++) fma32(o, in0[k], w1 + k*H + half*32);
    float4* tw = (float4*)(t + (size_t)v*H + half*32);
    #pragma unroll
    for (int j4=0;j4<8;j4++){
      float4 q;
      q.x = relu_(o[4*j4+0]); q.y = relu_(o[4*j4+1]);
      q.z = relu_(o[4*j4+2]); q.w = relu_(o[4*j4+3]);
      tw[j4] = q;
    }
  }
}

// ---------------- generic 64->64 relu MLP layer: out = relu(in@w+b) ----------------
__global__ __launch_bounds__(256) void mlp64_kernel(
    const float* __restrict__ in,
    const float* __restrict__ w, const float* __restrict__ b,
    float* __restrict__ outb)
{
  int v = blockIdx.x*256 + threadIdx.x;
  if (v >= NN) return;
  const float4* iv = (const float4*)(in + (size_t)v*H);
  #pragma unroll 1
  for (int half=0; half<2; half++){
    float o[32];
    #pragma unroll
    for (int j=0;j<32;j++) o[j] = b[half*32 + j];
    #pragma unroll 4
    for (int k4=0;k4<16;k4++){
      float4 a = iv[k4];
      const float* wr = w + (4*k4)*H + half*32;
      fma32(o, a.x, wr); fma32(o, a.y, wr+H); fma32(o, a.z, wr+2*H); fma32(o, a.w, wr+3*H);
    }
    float4* ow = (float4*)(outb + (size_t)v*H + half*32);
    #pragma unroll
    for (int j4=0;j4<8;j4++){
      float4 q;
      q.x = relu_(o[4*j4+0]); q.y = relu_(o[4*j4+1]);
      q.z = relu_(o[4*j4+2]); q.w = relu_(o[4*j4+3]);
      ow[j4] = q;
    }
  }
}

// ---------------- in-degree counts ----------------
__global__ __launch_bounds__(256) void deg_kernel(const int* __restrict__ dst,
                                                  int* __restrict__ counts)
{
  int e = blockIdx.x*256 + threadIdx.x;
  if (e < NE) atomicAdd(&counts[dst[e]], 1);
}

// ---------------- 3-phase scan: phase 1 (per-1024-chunk exclusive scan) ----------------
__global__ __launch_bounds__(1024) void scan1_kernel(const int* __restrict__ counts,
                                                     int* __restrict__ row_excl,
                                                     int* __restrict__ part)
{
  __shared__ int buf[1024];
  int tid = threadIdx.x;
  int i = blockIdx.x*1024 + tid;
  int v = (i < NN) ? counts[i] : 0;
  buf[tid] = v;
  __syncthreads();
  for (int off=1; off<1024; off<<=1){
    int t = (tid >= off) ? buf[tid-off] : 0;
    __syncthreads();
    buf[tid] += t;
    __syncthreads();
  }
  if (i < NN) row_excl[i] = buf[tid] - v;
  if (tid == 1023) part[blockIdx.x] = buf[1023];
}

// ---------------- phase 2: exclusive scan of 98 partials ----------------
__global__ __launch_bounds__(128) void scan2_kernel(int* __restrict__ part, int nparts)
{
  __shared__ int buf[128];
  int tid = threadIdx.x;
  int v = (tid < nparts) ? part[tid] : 0;
  buf[tid] = v;
  __syncthreads();
  for (int off=1; off<128; off<<=1){
    int t = (tid >= off) ? buf[tid-off] : 0;
    __syncthreads();
    buf[tid] += t;
    __syncthreads();
  }
  if (tid < nparts) part[tid] = buf[tid] - v;
}

// ---------------- fill dst-sorted src/dst arrays ----------------
__global__ __launch_bounds__(256) void fill_kernel(
    const int* __restrict__ src, const int* __restrict__ dst,
    const int* __restrict__ row_excl, const int* __restrict__ part,
    int* __restrict__ cursor, int* __restrict__ ssrc, int* __restrict__ sdst)
{
  int e = blockIdx.x*256 + threadIdx.x;
  if (e >= NE) return;
  int d = dst[e];
  int base = row_excl[d] + part[d >> 10];
  int p = base + atomicAdd(&cursor[d], 1);
  ssrc[p] = src[e];
  sdst[p] = d;
}

// ---------------- P projection: P[v] = bf16([h@w1_top || h@w1_bot]) ----------------
__global__ __launch_bounds__(256) void pproj_kernel(
    const float* __restrict__ h, const float* __restrict__ w1,
    unsigned short* __restrict__ P)
{
  int v = blockIdx.x*256 + threadIdx.x;
  if (v >= NN) return;
  const float4* hv = (const float4*)(h + (size_t)v*H);
  unsigned short* Pr = P + (size_t)v*128;
  #pragma unroll 1
  for (int q=0; q<4; q++){
    const float* w = w1 + ((q>>1)*64)*H + (q&1)*32;
    float o[32];
    #pragma unroll
    for (int j=0;j<32;j++) o[j] = 0.0f;
    #pragma unroll 4
    for (int k4=0;k4<16;k4++){
      float4 a = hv[k4];
      const float* wr = w + (4*k4)*H;
      fma32(o, a.x, wr); fma32(o, a.y, wr+H); fma32(o, a.z, wr+2*H); fma32(o, a.w, wr+3*H);
    }
    unsigned int* dp = (unsigned int*)(Pr + (q>>1)*64 + (q&1)*32);
    #pragma unroll
    for (int j=0;j<16;j++)
      dp[j] = (unsigned int)f2b_(o[2*j]) | ((unsigned int)f2b_(o[2*j+1]) << 16);
  }
}

// ---------------- fused message MLP + in-block segmented reduce ----------------
// sorted edges; hid = relu(P1[src]+P2[dst]+b1); m = relu(hid@w2+b2);
// per-block segmented sum by dst; interior runs plain-store, boundary runs atomicAdd.
__global__ __launch_bounds__(MBK) void msg_agg_kernel(
    const unsigned short* __restrict__ P,
    const int* __restrict__ ssrc, const int* __restrict__ sdst,
    const float* __restrict__ b1, const float* __restrict__ w2,
    const float* __restrict__ b2,
    float* __restrict__ agg)
{
  __shared__ float red[2*MBK*SLOT];
  __shared__ int dloc[MBK];
  int t = threadIdx.x;
  int p = blockIdx.x*MBK + t;
  bool valid = p < NE;
  int s = valid ? ssrc[p] : 0;
  int d = valid ? sdst[p] : -1;
  dloc[t] = d;
  const unsigned short* Pr = P + (size_t)s*128;

  #pragma unroll 1
  for (int g=0; g<2; g++){
    float o[32];
    #pragma unroll
    for (int j=0;j<32;j++) o[j] = b2[g*32 + j];
    #pragma unroll 2
    for (int k4=0;k4<16;k4++){
      uint2 u1 = *(const uint2*)(Pr + 4*k4);        // p1[4k4..4k4+3] bf16
      uint2 u2 = *(const uint2*)(Pr + 64 + 4*k4);   // p2[4k4..4k4+3] bf16
      float h0 = relu_(b2f_((unsigned short)(u1.x & 0xffffu)) + b2f_((unsigned short)(u2.x & 0xffffu)) + b1[4*k4+0]);
      float h1 = relu_(b2f_((unsigned short)(u1.x >> 16))     + b2f_((unsigned short)(u2.x >> 16))     + b1[4*k4+1]);
      float h2 = relu_(b2f_((unsigned short)(u1.y & 0xffffu)) + b2f_((unsigned short)(u2.y & 0xffffu)) + b1[4*k4+2]);
      float h3 = relu_(b2f_((unsigned short)(u1.y >> 16))     + b2f_((unsigned short)(u2.y >> 16))     + b1[4*k4+3]);
      const float* wr = w2 + (4*k4)*H + g*32;
      fma32(o, h0, wr); fma32(o, h1, wr+H); fma32(o, h2, wr+2*H); fma32(o, h3, wr+3*H);
    }
    float* slab = red + g*MBK*SLOT + t*SLOT;
    #pragma unroll
    for (int j=0;j<32;j++) slab[j] = relu_(o[j]);   // message output relu
  }
  __syncthreads();

  if (t < 64){
    int j = t;
    const float* base = red + (j < 32 ? 0 : MBK*SLOT) + (j & 31);
    float acc = 0.0f;
    int cur = dloc[0];
    bool firstRun = true;
    #pragma unroll 4
    for (int r=0; r<MBK; r++){
      int dr = dloc[r];
      if (dr != cur){
        if (cur >= 0){
          if (firstRun) atomicAdd(&agg[(size_t)cur*H + j], acc);
          else          agg[(size_t)cur*H + j] = acc;
        }
        firstRun = false;
        acc = 0.0f;
        cur = dr;
      }
      acc += base[(size_t)r*SLOT];
    }
    if (cur >= 0) atomicAdd(&agg[(size_t)cur*H + j], acc);  // last run: always boundary
  }
}

// ---------------- update stage A: t = relu([h || agg/deg]@w1 + b1) ----------------
__global__ __launch_bounds__(256) void upd_a_kernel(
    const float* __restrict__ h, const float* __restrict__ agg,
    const int* __restrict__ counts,
    const float* __restrict__ w1, const float* __restrict__ b1,
    float* __restrict__ t)
{
  int v = blockIdx.x*256 + threadIdx.x;
  if (v >= NN) return;
  float invd = 1.0f / fmaxf((float)counts[v], 1.0f);
  const float4* hv = (const float4*)(h   + (size_t)v*H);
  const float4* av = (const float4*)(agg + (size_t)v*H);
  #pragma unroll 1
  for (int half=0; half<2; half++){
    float o[32];
    #pragma unroll
    for (int j=0;j<32;j++) o[j] = b1[half*32 + j];
    #pragma unroll 4
    for (int k4=0;k4<16;k4++){
      float4 a = hv[k4];
      const float* wr = w1 + (4*k4)*H + half*32;
      fma32(o, a.x, wr); fma32(o, a.y, wr+H); fma32(o, a.z, wr+2*H); fma32(o, a.w, wr+3*H);
    }
    #pragma unroll 4
    for (int k4=0;k4<16;k4++){
      float4 a = av[k4];
      float ax = a.x*invd, ay = a.y*invd, az = a.z*invd, aw = a.w*invd;
      const float* wr = w1 + (64 + 4*k4)*H + half*32;
      fma32(o, ax, wr); fma32(o, ay, wr+H); fma32(o, az, wr+2*H); fma32(o, aw, wr+3*H);
    }
    float4* tw = (float4*)(t + (size_t)v*H + half*32);
    #pragma unroll
    for (int j4=0;j4<8;j4++){
      float4 q;
      q.x = relu_(o[4*j4+0]); q.y = relu_(o[4*j4+1]);
      q.z = relu_(o[4*j4+2]); q.w = relu_(o[4*j4+3]);
      tw[j4] = q;
    }
  }
}

// ---------------- output head ----------------
__global__ __launch_bounds__(256) void out_kernel2(
    const float* __restrict__ h,
    const float* __restrict__ w1, const float* __restrict__ b1,
    const float* __restrict__ w2, const float* __restrict__ b2,
    float* __restrict__ out)
{
  int v = blockIdx.x*256 + threadIdx.x;
  if (v >= NN) return;
  const float4* hv = (const float4*)(h + (size_t)v*H);
  float pr[3] = { b2[0], b2[1], b2[2] };
  #pragma unroll 1
  for (int half=0; half<2; half++){
    float o[32];
    #pragma unroll
    for (int j=0;j<32;j++) o[j] = b1[half*32 + j];
    #pragma unroll 4
    for (int k4=0;k4<16;k4++){
      float4 a = hv[k4];
      const float* wr = w1 + (4*k4)*H + half*32;
      fma32(o, a.x, wr); fma32(o, a.y, wr+H); fma32(o, a.z, wr+2*H); fma32(o, a.w, wr+3*H);
    }
    #pragma unroll
    for (int j=0;j<32;j++){
      float hk = relu_(o[j]);
      int k = half*32 + j;
      pr[0] = fmaf(hk, w2[k*3+0], pr[0]);
      pr[1] = fmaf(hk, w2[k*3+1], pr[1]);
      pr[2] = fmaf(hk, w2[k*3+2], pr[2]);
    }
  }
  #pragma unroll
  for (int c=0;c<3;c++)
    out[(size_t)v*3 + c] = 6.283185307179586f / (1.0f + __expf(-pr[c]));
}

// ================= legacy fallback kernels (known correct; small ws) =================
__global__ __launch_bounds__(256) void enc_kernel_legacy(
    const float* __restrict__ x,
    const float* __restrict__ w1, const float* __restrict__ b1,
    const float* __restrict__ w2, const float* __restrict__ b2,
    float* __restrict__ h)
{
  int v = blockIdx.x*256 + threadIdx.x;
  if (v >= NN) return;
  float in0[5];
  #pragma unroll
  for (int k=0;k<5;k++) in0[k] = x[v*5+k];
  float hid[H];
  #pragma unroll
  for (int j=0;j<H;j++) hid[j] = b1[j];
  #pragma unroll
  for (int k=0;k<5;k++){
    #pragma unroll
    for (int j=0;j<H;j++) hid[j] = fmaf(in0[k], w1[k*H+j], hid[j]);
  }
  float o[H];
  #pragma unroll
  for (int j=0;j<H;j++) o[j] = b2[j];
  #pragma unroll
  for (int k=0;k<H;k++){
    float hk = relu_(hid[k]);
    #pragma unroll
    for (int j=0;j<H;j++) o[j] = fmaf(hk, w2[k*H+j], o[j]);
  }
  float4* hw = (float4*)(h + (size_t)v*H);
  #pragma unroll
  for (int j4=0;j4<H/4;j4++){
    float4 t;
    t.x = relu_(o[4*j4+0]); t.y = relu_(o[4*j4+1]);
    t.z = relu_(o[4*j4+2]); t.w = relu_(o[4*j4+3]);
    hw[j4] = t;
  }
}

__global__ __launch_bounds__(256) void msg_kernel_atomic(
    const float* __restrict__ h,
    const int* __restrict__ src, const int* __restrict__ dst,
    const float* __restrict__ w1, const float* __restrict__ b1,
    const float* __restrict__ w2, const float* __restrict__ b2,
    float* __restrict__ agg)
{
  int e = blockIdx.x*256 + threadIdx.x;
  if (e >= NE) return;
  int s = src[e], d = dst[e];
  const float4* hs = (const float4*)(h + (size_t)s*H);
  const float4* hd = (const float4*)(h + (size_t)d*H);
  float hid[H];
  #pragma unroll
  for (int j=0;j<H;j++) hid[j] = b1[j];
  #pragma unroll 4
  for (int k4=0;k4<16;k4++){
    float4 a = hs[k4];
    const float* wr = w1 + (size_t)(4*k4)*H;
    #pragma unroll
    for (int j=0;j<H;j++) hid[j] = fmaf(a.x, wr[j], hid[j]);
    #pragma unroll
    for (int j=0;j<H;j++) hid[j] = fmaf(a.y, wr[H+j], hid[j]);
    #pragma unroll
    for (int j=0;j<H;j++) hid[j] = fmaf(a.z, wr[2*H+j], hid[j]);
    #pragma unroll
    for (int j=0;j<H;j++) hid[j] = fmaf(a.w, wr[3*H+j], hid[j]);
  }
  #pragma unroll 4
  for (int k4=0;k4<16;k4++){
    float4 a = hd[k4];
    const float* wr = w1 + (size_t)(64 + 4*k4)*H;
    #pragma unroll
    for (int j=0;j<H;j++) hid[j] = fmaf(a.x, wr[j], hid[j]);
    #pragma unroll
    for (int j=0;j<H;j++) hid[j] = fmaf(a.y, wr[H+j], hid[j]);
    #pragma unroll
    for (int j=0;j<H;j++) hid[j] = fmaf(a.z, wr[2*H+j], hid[j]);
    #pragma unroll
    for (int j=0;j<H;j++) hid[j] = fmaf(a.w, wr[3*H+j], hid[j]);
  }
  float o[H];
  #pragma unroll
  for (int j=0;j<H;j++) o[j] = b2[j];
  #pragma unroll
  for (int k=0;k<H;k++){
    float hk = relu_(hid[k]);
    #pragma unroll
    for (int j=0;j<H;j++) o[j] = fmaf(hk, w2[k*H+j], o[j]);
  }
  float* arow = agg + (size_t)d*H;
  #pragma unroll
  for (int j=0;j<H;j++) atomicAdd(arow + j, relu_(o[j]));
}

__global__ __launch_bounds__(256) void div_kernel(float* __restrict__ agg,
                                                  const int* __restrict__ counts)
{
  int i = blockIdx.x*256 + threadIdx.x;
  if (i >= NN*H/4) return;
  int v = i / (H/4);
  float invd = 1.0f / fmaxf((float)counts[v], 1.0f);
  float4* a = (float4*)agg + i;
  float4 t = *a;
  t.x *= invd; t.y *= invd; t.z *= invd; t.w *= invd;
  *a = t;
}

__global__ __launch_bounds__(256) void upd_kernel_legacy(
    float* __restrict__ h, const float* __restrict__ agg,
    const float* __restrict__ w1, const float* __restrict__ b1,
    const float* __restrict__ w2, const float* __restrict__ b2)
{
  int v = blockIdx.x*256 + threadIdx.x;
  if (v >= NN) return;
  const float4* hv = (const float4*)(h + (size_t)v*H);
  const float4* av = (const float4*)(agg + (size_t)v*H);
  float hid[H];
  #pragma unroll
  for (int j=0;j<H;j++) hid[j] = b1[j];
  #pragma unroll 4
  for (int k4=0;k4<16;k4++){
    float4 a = hv[k4];
    const float* wr = w1 + (size_t)(4*k4)*H;
    #pragma unroll
    for (int j=0;j<H;j++) hid[j] = fmaf(a.x, wr[j], hid[j]);
    #pragma unroll
    for (int j=0;j<H;j++) hid[j] = fmaf(a.y, wr[H+j], hid[j]);
    #pragma unroll
    for (int j=0;j<H;j++) hid[j] = fmaf(a.z, wr[2*H+j], hid[j]);
    #pragma unroll
    for (int j=0;j<H;j++) hid[j] = fmaf(a.w, wr[3*H+j], hid[j]);
  }
  #pragma unroll 4
  for (int k4=0;k4<16;k4++){
    float4 a = av[k4];
    const float* wr = w1 + (size_t)(64 + 4*k4)*H;
    #pragma unroll
    for (int j=0;j<H;j++) hid[j] = fmaf(a.x, wr[j], hid[j]);
    #pragma unroll
    for (int j=0;j<H;j++) hid[j] = fmaf(a.y, wr[H+j], hid[j]);
    #pragma unroll
    for (int j=0;j<H;j++) hid[j] = fmaf(a.z, wr[2*H+j], hid[j]);
    #pragma unroll
    for (int j=0;j<H;j++) hid[j] = fmaf(a.w, wr[3*H+j], hid[j]);
  }
  float o[H];
  #pragma unroll
  for (int j=0;j<H;j++) o[j] = b2[j];
  #pragma unroll
  for (int k=0;k<H;k++){
    float hk = relu_(hid[k]);
    #pragma unroll
    for (int j=0;j<H;j++) o[j] = fmaf(hk, w2[k*H+j], o[j]);
  }
  float4* hw = (float4*)(h + (size_t)v*H);
  #pragma unroll
  for (int j4=0;j4<H/4;j4++){
    float4 t;
    t.x = relu_(o[4*j4+0]); t.y = relu_(o[4*j4+1]);
    t.z = relu_(o[4*j4+2]); t.w = relu_(o[4*j4+3]);
    hw[j4] = t;
  }
}

// =====================================================================

extern "C" void kernel_launch(void* const* d_in, const int* in_sizes, int n_in,
                              void* d_out, int out_size, void* d_ws, size_t ws_size,
                              hipStream_t stream)
{
  const float* x      = (const float*)d_in[0];
  const int*   ei     = (const int*)  d_in[1];
  const float* enc_w1 = (const float*)d_in[2];
  const float* enc_b1 = (const float*)d_in[3];
  const float* enc_w2 = (const float*)d_in[4];
  const float* enc_b2 = (const float*)d_in[5];
  const float* msg_w1 = (const float*)d_in[6];
  const float* msg_b1 = (const float*)d_in[7];
  const float* msg_w2 = (const float*)d_in[8];
  const float* msg_b2 = (const float*)d_in[9];
  const float* upd_w1 = (const float*)d_in[10];
  const float* upd_b1 = (const float*)d_in[11];
  const float* upd_w2 = (const float*)d_in[12];
  const float* upd_b2 = (const float*)d_in[13];
  const float* out_w1 = (const float*)d_in[14];
  const float* out_b1 = (const float*)d_in[15];
  const float* out_w2 = (const float*)d_in[16];
  const float* out_b2 = (const float*)d_in[17];
  float* out = (float*)d_out;

  const int* srcp = ei;
  const int* dstp = ei + NE;

  const int nodeBlocks = (NN + 255)/256;
  const int edgeBlocks = (NE + 255)/256;
  const int msgBlocks  = (NE + MBK - 1)/MBK;
  const int scanBlocks = (NN + 1023)/1024;   // 98

  // ---- workspace layout (aligned to 256B) ----
  char* wp = (char*)d_ws;
  auto take = [&wp](size_t bytes) -> char* {
    char* r = wp;
    wp += (bytes + 255) & ~(size_t)255;
    return r;
  };
  float* h            = (float*)take((size_t)NN*H*sizeof(float));        // 25.6 MB
  unsigned short* P   = (unsigned short*)take((size_t)NN*128*sizeof(unsigned short)); // 25.6 MB
  float* tmp          = (float*)P;  // alias: tmp [NN*64] f32 == P size; disjoint lifetime
  float* agg          = (float*)take((size_t)NN*H*sizeof(float));        // 25.6 MB
  int* counts         = (int*)take((size_t)NN*sizeof(int));
  int* cursor         = (int*)take((size_t)NN*sizeof(int));
  int* row_excl       = (int*)take((size_t)NN*sizeof(int));
  int* part           = (int*)take(1024);
  int* ssrc           = (int*)take((size_t)NE*sizeof(int));
  int* sdst           = (int*)take((size_t)NE*sizeof(int));
  size_t need = (size_t)(wp - (char*)d_ws);

  if (ws_size >= need) {
    // ======== fast path: factored message MLP + sorted segmented reduce ========
    hipMemsetAsync(counts, 0, NN*sizeof(int), stream);
    hipMemsetAsync(cursor, 0, NN*sizeof(int), stream);

    enc_a_kernel<<<nodeBlocks, 256, 0, stream>>>(x, enc_w1, enc_b1, tmp);
    mlp64_kernel<<<nodeBlocks, 256, 0, stream>>>(tmp, enc_w2, enc_b2, h);

    deg_kernel<<<edgeBlocks, 256, 0, stream>>>(dstp, counts);
    scan1_kernel<<<scanBlocks, 1024, 0, stream>>>(counts, row_excl, part);
    scan2_kernel<<<1, 128, 0, stream>>>(part, scanBlocks);
    fill_kernel<<<edgeBlocks, 256, 0, stream>>>(srcp, dstp, row_excl, part, cursor, ssrc, sdst);

    for (int l=0; l<3; l++){
      pproj_kernel<<<nodeBlocks, 256, 0, stream>>>(h, msg_w1 + (size_t)l*128*H, P);
      hipMemsetAsync(agg, 0, (size_t)NN*H*sizeof(float), stream);
      msg_agg_kernel<<<msgBlocks, MBK, 0, stream>>>(P, ssrc, sdst,
          msg_b1 + (size_t)l*H, msg_w2 + (size_t)l*H*H, msg_b2 + (size_t)l*H, agg);
      upd_a_kernel<<<nodeBlocks, 256, 0, stream>>>(h, agg, counts,
          upd_w1 + (size_t)l*128*H, upd_b1 + (size_t)l*H, tmp);
      mlp64_kernel<<<nodeBlocks, 256, 0, stream>>>(tmp,
          upd_w2 + (size_t)l*H*H, upd_b2 + (size_t)l*H, h);
    }
    out_kernel2<<<nodeBlocks, 256, 0, stream>>>(h, out_w1, out_b1, out_w2, out_b2, out);
  } else {
    // ======== fallback: legacy atomic path (fits in ~52 MB) ========
    char* fp = (char*)d_ws;
    float* fh   = (float*)fp;  fp += (size_t)NN*H*sizeof(float);
    float* fagg = (float*)fp;  fp += (size_t)NN*H*sizeof(float);
    int* fcnt   = (int*)fp;

    hipMemsetAsync(fcnt, 0, NN*sizeof(int), stream);
    enc_kernel_legacy<<<nodeBlocks, 256, 0, stream>>>(x, enc_w1, enc_b1, enc_w2, enc_b2, fh);
    deg_kernel<<<edgeBlocks, 256, 0, stream>>>(dstp, fcnt);
    for (int l=0; l<3; l++){
      hipMemsetAsync(fagg, 0, (size_t)NN*H*sizeof(float), stream);
      msg_kernel_atomic<<<edgeBlocks, 256, 0, stream>>>(fh, srcp, dstp,
          msg_w1 + (size_t)l*128*H, msg_b1 + (size_t)l*H,
          msg_w2 + (size_t)l*H*H,   msg_b2 + (size_t)l*H, fagg);
      div_kernel<<<(NN*H/4 + 255)/256, 256, 0, stream>>>(fagg, fcnt);
      upd_kernel_legacy<<<nodeBlocks, 256, 0, stream>>>(fh, fagg,
          upd_w1 + (size_t)l*128*H, upd_b1 + (size_t)l*H,
          upd_w2 + (size_t)l*H*H,   upd_b2 + (size_t)l*H);
    }
    out_kernel2<<<nodeBlocks, 256, 0, stream>>>(fh, out_w1, out_b1, out_w2, out_b2, out);
  }
}

// Round 4
// 1389.538 us; speedup vs baseline: 7.6685x; 1.1977x over previous
//
#include <hip/hip_runtime.h>
#include <math.h>

#define NN 100000
#define NE 1000000
#define H 64
#define MSTRIDE 258   // ushorts per channel row in msg LDS (256 edges + 2 pad)

typedef short bf16x8 __attribute__((ext_vector_type(8)));
typedef float f32x4  __attribute__((ext_vector_type(4)));

static __device__ __forceinline__ float relu_(float x){ return fmaxf(x, 0.0f); }

static __device__ __forceinline__ float b2f_(unsigned short u){
  union { float f; unsigned int i; } v; v.i = ((unsigned int)u) << 16; return v.f;
}
static __device__ __forceinline__ unsigned short f2b_(float f){
  union { float f; unsigned int i; } v; v.f = f;
  unsigned int r = (v.i + 0x7FFFu + ((v.i >> 16) & 1u)) >> 16;
  return (unsigned short)r;
}
static __device__ __forceinline__ unsigned int asu_(float f){
  union { float f; unsigned int i; } v; v.f = f; return v.i;
}
static __device__ __forceinline__ float asf_(unsigned int u){
  union { float f; unsigned int i; } v; v.i = u; return v.f;
}

static __device__ __forceinline__ void fma32(float* o, float a, const float* wr){
  #pragma unroll
  for (int j=0;j<32;j++) o[j] = fmaf(a, wr[j], o[j]);
}

// ---------------- encoder stage A: t = relu(x@w1+b1), x:[N,5] ----------------
__global__ __launch_bounds__(256) void enc_a_kernel(
    const float* __restrict__ x,
    const float* __restrict__ w1, const float* __restrict__ b1,
    float* __restrict__ t)
{
  int v = blockIdx.x*256 + threadIdx.x;
  if (v >= NN) return;
  float in0[5];
  #pragma unroll
  for (int k=0;k<5;k++) in0[k] = x[(size_t)v*5 + k];
  #pragma unroll 1
  for (int half=0; half<2; half++){
    float o[32];
    #pragma unroll
    for (int j=0;j<32;j++) o[j] = b1[half*32 + j];
    #pragma unroll
    for (int k=0;k<5;k++) fma32(o, in0[k], w1 + k*H + half*32);
    float4* tw = (float4*)(t + (size_t)v*H + half*32);
    #pragma unroll
    for (int j4=0;j4<8;j4++){
      float4 q;
      q.x = relu_(o[4*j4+0]); q.y = relu_(o[4*j4+1]);
      q.z = relu_(o[4*j4+2]); q.w = relu_(o[4*j4+3]);
      tw[j4] = q;
    }
  }
}

// ---------------- generic 64->64 relu MLP layer: out = relu(in@w+b) ----------------
__global__ __launch_bounds__(256) void mlp64_kernel(
    const float* __restrict__ in,
    const float* __restrict__ w, const float* __restrict__ b,
    float* __restrict__ outb)
{
  int v = blockIdx.x*256 + threadIdx.x;
  if (v >= NN) return;
  const float4* iv = (const float4*)(in + (size_t)v*H);
  #pragma unroll 1
  for (int half=0; half<2; half++){
    float o[32];
    #pragma unroll
    for (int j=0;j<32;j++) o[j] = b[half*32 + j];
    #pragma unroll 4
    for (int k4=0;k4<16;k4++){
      float4 a = iv[k4];
      const float* wr = w + (4*k4)*H + half*32;
      fma32(o, a.x, wr); fma32(o, a.y, wr+H); fma32(o, a.z, wr+2*H); fma32(o, a.w, wr+3*H);
    }
    float4* ow = (float4*)(outb + (size_t)v*H + half*32);
    #pragma unroll
    for (int j4=0;j4<8;j4++){
      float4 q;
      q.x = relu_(o[4*j4+0]); q.y = relu_(o[4*j4+1]);
      q.z = relu_(o[4*j4+2]); q.w = relu_(o[4*j4+3]);
      ow[j4] = q;
    }
  }
}

// ---------------- in-degree counts ----------------
__global__ __launch_bounds__(256) void deg_kernel(const int* __restrict__ dst,
                                                  int* __restrict__ counts)
{
  int e = blockIdx.x*256 + threadIdx.x;
  if (e < NE) atomicAdd(&counts[dst[e]], 1);
}

// ---------------- scan phase 1 ----------------
__global__ __launch_bounds__(1024) void scan1_kernel(const int* __restrict__ counts,
                                                     int* __restrict__ row_excl,
                                                     int* __restrict__ part)
{
  __shared__ int buf[1024];
  int tid = threadIdx.x;
  int i = blockIdx.x*1024 + tid;
  int v = (i < NN) ? counts[i] : 0;
  buf[tid] = v;
  __syncthreads();
  for (int off=1; off<1024; off<<=1){
    int t = (tid >= off) ? buf[tid-off] : 0;
    __syncthreads();
    buf[tid] += t;
    __syncthreads();
  }
  if (i < NN) row_excl[i] = buf[tid] - v;
  if (tid == 1023) part[blockIdx.x] = buf[1023];
}

// ---------------- scan phase 2 ----------------
__global__ __launch_bounds__(128) void scan2_kernel(int* __restrict__ part, int nparts)
{
  __shared__ int buf[128];
  int tid = threadIdx.x;
  int v = (tid < nparts) ? part[tid] : 0;
  buf[tid] = v;
  __syncthreads();
  for (int off=1; off<128; off<<=1){
    int t = (tid >= off) ? buf[tid-off] : 0;
    __syncthreads();
    buf[tid] += t;
    __syncthreads();
  }
  if (tid < nparts) part[tid] = buf[tid] - v;
}

// ---------------- fill dst-sorted src/dst arrays ----------------
__global__ __launch_bounds__(256) void fill_kernel(
    const int* __restrict__ src, const int* __restrict__ dst,
    const int* __restrict__ row_excl, const int* __restrict__ part,
    int* __restrict__ cursor, int* __restrict__ ssrc, int* __restrict__ sdst)
{
  int e = blockIdx.x*256 + threadIdx.x;
  if (e >= NE) return;
  int d = dst[e];
  int base = row_excl[d] + part[d >> 10];
  int p = base + atomicAdd(&cursor[d], 1);
  ssrc[p] = src[e];
  sdst[p] = d;
}

// ---------------- P projection: P[v] = bf16([h@w1_top || h@w1_bot + b1]) ----------------
// b1 is folded into the P2 half.
__global__ __launch_bounds__(256) void pproj_kernel(
    const float* __restrict__ h, const float* __restrict__ w1,
    const float* __restrict__ b1,
    unsigned short* __restrict__ P)
{
  int v = blockIdx.x*256 + threadIdx.x;
  if (v >= NN) return;
  const float4* hv = (const float4*)(h + (size_t)v*H);
  unsigned short* Pr = P + (size_t)v*128;
  #pragma unroll 1
  for (int q=0; q<4; q++){
    const float* w = w1 + ((q>>1)*64)*H + (q&1)*32;
    float o[32];
    #pragma unroll
    for (int j=0;j<32;j++) o[j] = (q >= 2) ? b1[(q&1)*32 + j] : 0.0f;
    #pragma unroll 4
    for (int k4=0;k4<16;k4++){
      float4 a = hv[k4];
      const float* wr = w + (4*k4)*H;
      fma32(o, a.x, wr); fma32(o, a.y, wr+H); fma32(o, a.z, wr+2*H); fma32(o, a.w, wr+3*H);
    }
    unsigned int* dp = (unsigned int*)(Pr + (q>>1)*64 + (q&1)*32);
    #pragma unroll
    for (int j=0;j<16;j++)
      dp[j] = (unsigned int)f2b_(o[2*j]) | ((unsigned int)f2b_(o[2*j+1]) << 16);
  }
}

// ---------------- w2 -> bf16 B-fragment swizzle (all 3 layers at once) ----------------
// Layout: w2p[l*4096 + (g*64 + n)*8 + j] = bf16(w2[l][k][n]), k = (g>>2)*32 + (g&3)*8 + j
__global__ __launch_bounds__(256) void w2prep_kernel(const float* __restrict__ w2,
                                                     unsigned short* __restrict__ w2p)
{
  int i = blockIdx.x*256 + threadIdx.x;
  if (i >= 3*4096) return;
  int l = i >> 12;
  int r = i & 4095;
  int j = r & 7, n = (r >> 3) & 63, g = r >> 9;
  int k = (g >> 2)*32 + (g & 3)*8 + j;
  w2p[i] = f2b_(w2[(size_t)l*4096 + k*64 + n]);
}

// ---------------- MFMA message kernel: 256 sorted edges/block + segmented reduce ------
// hid = relu(P1[src] + P2[dst])  (b1 folded into P2), bf16 A-frags built in-register.
// m = relu(hid @ w2 + b2) via mfma_f32_16x16x32_bf16; m -> LDS bf16 [ch][edge];
// 4x64-edge chunk segmented sum: interior runs store, boundary runs atomicAdd.
__global__ __launch_bounds__(256, 2) void msg_mfma_kernel(
    const unsigned short* __restrict__ P,
    const unsigned short* __restrict__ w2p,
    const float* __restrict__ b2,
    const int* __restrict__ ssrc, const int* __restrict__ sdst,
    float* __restrict__ agg)
{
  __shared__ unsigned short mlds[64*MSTRIDE];
  __shared__ int sloc[256], dloc[256];
  const int tid  = threadIdx.x;
  const int wave = tid >> 6, lane = tid & 63, quad = lane >> 4, c = lane & 15;

  int p = blockIdx.x*256 + tid;
  int sv = 0, dv = -1;
  if (p < NE){ sv = ssrc[p]; dv = sdst[p]; }
  sloc[tid] = sv; dloc[tid] = dv;

  // B fragments: lane holds w2[k = kb*32 + quad*8 + j][n = n*16 + c]
  bf16x8 bfr[4][2];
  #pragma unroll
  for (int n=0;n<4;n++)
    #pragma unroll
    for (int kb=0;kb<2;kb++)
      bfr[n][kb] = *(const bf16x8*)(w2p + (((kb*4 + quad)*64 + n*16 + c) << 3));

  float bv[4];
  #pragma unroll
  for (int n=0;n<4;n++) bv[n] = b2[n*16 + c];

  __syncthreads();

  f32x4 acc[4][4];
  #pragma unroll
  for (int t=0;t<4;t++)
    #pragma unroll
    for (int n=0;n<4;n++)
      acc[t][n] = (f32x4){0.f, 0.f, 0.f, 0.f};

  const int ebase = wave*64;
  #pragma unroll 1
  for (int t=0;t<4;t++){
    int s = sloc[ebase + t*16 + c];
    int d = dloc[ebase + t*16 + c];
    if (d < 0) d = 0;                       // tail lanes: harmless garbage
    const unsigned short* p1 = P + (size_t)s*128 + quad*8;
    const unsigned short* p2 = P + (size_t)d*128 + 64 + quad*8;
    bf16x8 af[2];
    #pragma unroll
    for (int kb=0;kb<2;kb++){
      uint4 u1 = *(const uint4*)(p1 + kb*32);
      uint4 u2 = *(const uint4*)(p2 + kb*32);
      unsigned int ua[4] = {u1.x, u1.y, u1.z, u1.w};
      unsigned int ub[4] = {u2.x, u2.y, u2.z, u2.w};
      union { unsigned int u[4]; bf16x8 v; } A;
      #pragma unroll
      for (int q2=0;q2<4;q2++){
        float lo = relu_(asf_(ua[q2] << 16)        + asf_(ub[q2] << 16));
        float hi = relu_(asf_(ua[q2] & 0xffff0000u) + asf_(ub[q2] & 0xffff0000u));
        A.u[q2] = (asu_(hi) & 0xffff0000u) | (asu_(lo) >> 16);
      }
      af[kb] = A.v;
    }
    #pragma unroll
    for (int n=0;n<4;n++){
      acc[t][n] = __builtin_amdgcn_mfma_f32_16x16x32_bf16(af[0], bfr[n][0], acc[t][n], 0, 0, 0);
      acc[t][n] = __builtin_amdgcn_mfma_f32_16x16x32_bf16(af[1], bfr[n][1], acc[t][n], 0, 0, 0);
    }
  }

  // epilogue: m = relu(acc + b2) -> bf16 LDS [ch][edge]
  // C layout: col(ch within tile) = lane&15, row(edge within tile) = quad*4 + reg
  #pragma unroll
  for (int t=0;t<4;t++){
    int e0 = ebase + t*16 + quad*4;
    #pragma unroll
    for (int n=0;n<4;n++){
      int ch = n*16 + c;
      float v0 = relu_(acc[t][n][0] + bv[n]);
      float v1 = relu_(acc[t][n][1] + bv[n]);
      float v2 = relu_(acc[t][n][2] + bv[n]);
      float v3 = relu_(acc[t][n][3] + bv[n]);
      unsigned int u01 = (asu_(v1) & 0xffff0000u) | (asu_(v0) >> 16);
      unsigned int u23 = (asu_(v3) & 0xffff0000u) | (asu_(v2) >> 16);
      *(unsigned int*)&mlds[ch*MSTRIDE + e0]     = u01;
      *(unsigned int*)&mlds[ch*MSTRIDE + e0 + 2] = u23;
    }
  }
  __syncthreads();

  // segmented reduce: thread = (chunk = tid>>6 over 64 edges, ch = tid&63)
  int ch = tid & 63;
  int cb = (tid >> 6) * 64;
  float s2 = 0.f; int cur = dloc[cb]; bool first = true;
  #pragma unroll 4
  for (int r=0;r<64;r++){
    int dr = dloc[cb + r];
    if (dr != cur){
      if (cur >= 0){
        if (first) atomicAdd(&agg[(size_t)cur*H + ch], s2);
        else       agg[(size_t)cur*H + ch] = s2;
      }
      first = false; s2 = 0.f; cur = dr;
    }
    s2 += b2f_(mlds[ch*MSTRIDE + cb + r]);
  }
  if (cur >= 0) atomicAdd(&agg[(size_t)cur*H + ch], s2);
}

// ---------------- update stage A: t = relu([h || agg/deg]@w1 + b1) ----------------
__global__ __launch_bounds__(256) void upd_a_kernel(
    const float* __restrict__ h, const float* __restrict__ agg,
    const int* __restrict__ counts,
    const float* __restrict__ w1, const float* __restrict__ b1,
    float* __restrict__ t)
{
  int v = blockIdx.x*256 + threadIdx.x;
  if (v >= NN) return;
  float invd = 1.0f / fmaxf((float)counts[v], 1.0f);
  const float4* hv = (const float4*)(h   + (size_t)v*H);
  const float4* av = (const float4*)(agg + (size_t)v*H);
  #pragma unroll 1
  for (int half=0; half<2; half++){
    float o[32];
    #pragma unroll
    for (int j=0;j<32;j++) o[j] = b1[half*32 + j];
    #pragma unroll 4
    for (int k4=0;k4<16;k4++){
      float4 a = hv[k4];
      const float* wr = w1 + (4*k4)*H + half*32;
      fma32(o, a.x, wr); fma32(o, a.y, wr+H); fma32(o, a.z, wr+2*H); fma32(o, a.w, wr+3*H);
    }
    #pragma unroll 4
    for (int k4=0;k4<16;k4++){
      float4 a = av[k4];
      float ax = a.x*invd, ay = a.y*invd, az = a.z*invd, aw = a.w*invd;
      const float* wr = w1 + (64 + 4*k4)*H + half*32;
      fma32(o, ax, wr); fma32(o, ay, wr+H); fma32(o, az, wr+2*H); fma32(o, aw, wr+3*H);
    }
    float4* tw = (float4*)(t + (size_t)v*H + half*32);
    #pragma unroll
    for (int j4=0;j4<8;j4++){
      float4 q;
      q.x = relu_(o[4*j4+0]); q.y = relu_(o[4*j4+1]);
      q.z = relu_(o[4*j4+2]); q.w = relu_(o[4*j4+3]);
      tw[j4] = q;
    }
  }
}

// ---------------- output head ----------------
__global__ __launch_bounds__(256) void out_kernel2(
    const float* __restrict__ h,
    const float* __restrict__ w1, const float* __restrict__ b1,
    const float* __restrict__ w2, const float* __restrict__ b2,
    float* __restrict__ out)
{
  int v = blockIdx.x*256 + threadIdx.x;
  if (v >= NN) return;
  const float4* hv = (const float4*)(h + (size_t)v*H);
  float pr[3] = { b2[0], b2[1], b2[2] };
  #pragma unroll 1
  for (int half=0; half<2; half++){
    float o[32];
    #pragma unroll
    for (int j=0;j<32;j++) o[j] = b1[half*32 + j];
    #pragma unroll 4
    for (int k4=0;k4<16;k4++){
      float4 a = hv[k4];
      const float* wr = w1 + (4*k4)*H + half*32;
      fma32(o, a.x, wr); fma32(o, a.y, wr+H); fma32(o, a.z, wr+2*H); fma32(o, a.w, wr+3*H);
    }
    #pragma unroll
    for (int j=0;j<32;j++){
      float hk = relu_(o[j]);
      int k = half*32 + j;
      pr[0] = fmaf(hk, w2[k*3+0], pr[0]);
      pr[1] = fmaf(hk, w2[k*3+1], pr[1]);
      pr[2] = fmaf(hk, w2[k*3+2], pr[2]);
    }
  }
  #pragma unroll
  for (int c=0;c<3;c++)
    out[(size_t)v*3 + c] = 6.283185307179586f / (1.0f + __expf(-pr[c]));
}

// ================= legacy fallback kernels (known correct; small ws) =================
__global__ __launch_bounds__(256) void enc_kernel_legacy(
    const float* __restrict__ x,
    const float* __restrict__ w1, const float* __restrict__ b1,
    const float* __restrict__ w2, const float* __restrict__ b2,
    float* __restrict__ h)
{
  int v = blockIdx.x*256 + threadIdx.x;
  if (v >= NN) return;
  float in0[5];
  #pragma unroll
  for (int k=0;k<5;k++) in0[k] = x[v*5+k];
  float hid[H];
  #pragma unroll
  for (int j=0;j<H;j++) hid[j] = b1[j];
  #pragma unroll
  for (int k=0;k<5;k++){
    #pragma unroll
    for (int j=0;j<H;j++) hid[j] = fmaf(in0[k], w1[k*H+j], hid[j]);
  }
  float o[H];
  #pragma unroll
  for (int j=0;j<H;j++) o[j] = b2[j];
  #pragma unroll
  for (int k=0;k<H;k++){
    float hk = relu_(hid[k]);
    #pragma unroll
    for (int j=0;j<H;j++) o[j] = fmaf(hk, w2[k*H+j], o[j]);
  }
  float4* hw = (float4*)(h + (size_t)v*H);
  #pragma unroll
  for (int j4=0;j4<H/4;j4++){
    float4 t;
    t.x = relu_(o[4*j4+0]); t.y = relu_(o[4*j4+1]);
    t.z = relu_(o[4*j4+2]); t.w = relu_(o[4*j4+3]);
    hw[j4] = t;
  }
}

__global__ __launch_bounds__(256) void msg_kernel_atomic(
    const float* __restrict__ h,
    const int* __restrict__ src, const int* __restrict__ dst,
    const float* __restrict__ w1, const float* __restrict__ b1,
    const float* __restrict__ w2, const float* __restrict__ b2,
    float* __restrict__ agg)
{
  int e = blockIdx.x*256 + threadIdx.x;
  if (e >= NE) return;
  int s = src[e], d = dst[e];
  const float4* hs = (const float4*)(h + (size_t)s*H);
  const float4* hd = (const float4*)(h + (size_t)d*H);
  float hid[H];
  #pragma unroll
  for (int j=0;j<H;j++) hid[j] = b1[j];
  #pragma unroll 4
  for (int k4=0;k4<16;k4++){
    float4 a = hs[k4];
    const float* wr = w1 + (size_t)(4*k4)*H;
    #pragma unroll
    for (int j=0;j<H;j++) hid[j] = fmaf(a.x, wr[j], hid[j]);
    #pragma unroll
    for (int j=0;j<H;j++) hid[j] = fmaf(a.y, wr[H+j], hid[j]);
    #pragma unroll
    for (int j=0;j<H;j++) hid[j] = fmaf(a.z, wr[2*H+j], hid[j]);
    #pragma unroll
    for (int j=0;j<H;j++) hid[j] = fmaf(a.w, wr[3*H+j], hid[j]);
  }
  #pragma unroll 4
  for (int k4=0;k4<16;k4++){
    float4 a = hd[k4];
    const float* wr = w1 + (size_t)(64 + 4*k4)*H;
    #pragma unroll
    for (int j=0;j<H;j++) hid[j] = fmaf(a.x, wr[j], hid[j]);
    #pragma unroll
    for (int j=0;j<H;j++) hid[j] = fmaf(a.y, wr[H+j], hid[j]);
    #pragma unroll
    for (int j=0;j<H;j++) hid[j] = fmaf(a.z, wr[2*H+j], hid[j]);
    #pragma unroll
    for (int j=0;j<H;j++) hid[j] = fmaf(a.w, wr[3*H+j], hid[j]);
  }
  float o[H];
  #pragma unroll
  for (int j=0;j<H;j++) o[j] = b2[j];
  #pragma unroll
  for (int k=0;k<H;k++){
    float hk = relu_(hid[k]);
    #pragma unroll
    for (int j=0;j<H;j++) o[j] = fmaf(hk, w2[k*H+j], o[j]);
  }
  float* arow = agg + (size_t)d*H;
  #pragma unroll
  for (int j=0;j<H;j++) atomicAdd(arow + j, relu_(o[j]));
}

__global__ __launch_bounds__(256) void div_kernel(float* __restrict__ agg,
                                                  const int* __restrict__ counts)
{
  int i = blockIdx.x*256 + threadIdx.x;
  if (i >= NN*H/4) return;
  int v = i / (H/4);
  float invd = 1.0f / fmaxf((float)counts[v], 1.0f);
  float4* a = (float4*)agg + i;
  float4 t = *a;
  t.x *= invd; t.y *= invd; t.z *= invd; t.w *= invd;
  *a = t;
}

__global__ __launch_bounds__(256) void upd_kernel_legacy(
    float* __restrict__ h, const float* __restrict__ agg,
    const float* __restrict__ w1, const float* __restrict__ b1,
    const float* __restrict__ w2, const float* __restrict__ b2)
{
  int v = blockIdx.x*256 + threadIdx.x;
  if (v >= NN) return;
  const float4* hv = (const float4*)(h + (size_t)v*H);
  const float4* av = (const float4*)(agg + (size_t)v*H);
  float hid[H];
  #pragma unroll
  for (int j=0;j<H;j++) hid[j] = b1[j];
  #pragma unroll 4
  for (int k4=0;k4<16;k4++){
    float4 a = hv[k4];
    const float* wr = w1 + (size_t)(4*k4)*H;
    #pragma unroll
    for (int j=0;j<H;j++) hid[j] = fmaf(a.x, wr[j], hid[j]);
    #pragma unroll
    for (int j=0;j<H;j++) hid[j] = fmaf(a.y, wr[H+j], hid[j]);
    #pragma unroll
    for (int j=0;j<H;j++) hid[j] = fmaf(a.z, wr[2*H+j], hid[j]);
    #pragma unroll
    for (int j=0;j<H;j++) hid[j] = fmaf(a.w, wr[3*H+j], hid[j]);
  }
  #pragma unroll 4
  for (int k4=0;k4<16;k4++){
    float4 a = av[k4];
    const float* wr = w1 + (size_t)(64 + 4*k4)*H;
    #pragma unroll
    for (int j=0;j<H;j++) hid[j] = fmaf(a.x, wr[j], hid[j]);
    #pragma unroll
    for (int j=0;j<H;j++) hid[j] = fmaf(a.y, wr[H+j], hid[j]);
    #pragma unroll
    for (int j=0;j<H;j++) hid[j] = fmaf(a.z, wr[2*H+j], hid[j]);
    #pragma unroll
    for (int j=0;j<H;j++) hid[j] = fmaf(a.w, wr[3*H+j], hid[j]);
  }
  float o[H];
  #pragma unroll
  for (int j=0;j<H;j++) o[j] = b2[j];
  #pragma unroll
  for (int k=0;k<H;k++){
    float hk = relu_(hid[k]);
    #pragma unroll
    for (int j=0;j<H;j++) o[j] = fmaf(hk, w2[k*H+j], o[j]);
  }
  float4* hw = (float4*)(h + (size_t)v*H);
  #pragma unroll
  for (int j4=0;j4<H/4;j4++){
    float4 t;
    t.x = relu_(o[4*j4+0]); t.y = relu_(o[4*j4+1]);
    t.z = relu_(o[4*j4+2]); t.w = relu_(o[4*j4+3]);
    hw[j4] = t;
  }
}

// =====================================================================

extern "C" void kernel_launch(void* const* d_in, const int* in_sizes, int n_in,
                              void* d_out, int out_size, void* d_ws, size_t ws_size,
                              hipStream_t stream)
{
  const float* x      = (const float*)d_in[0];
  const int*   ei     = (const int*)  d_in[1];
  const float* enc_w1 = (const float*)d_in[2];
  const float* enc_b1 = (const float*)d_in[3];
  const float* enc_w2 = (const float*)d_in[4];
  const float* enc_b2 = (const float*)d_in[5];
  const float* msg_w1 = (const float*)d_in[6];
  const float* msg_b1 = (const float*)d_in[7];
  const float* msg_w2 = (const float*)d_in[8];
  const float* msg_b2 = (const float*)d_in[9];
  const float* upd_w1 = (const float*)d_in[10];
  const float* upd_b1 = (const float*)d_in[11];
  const float* upd_w2 = (const float*)d_in[12];
  const float* upd_b2 = (const float*)d_in[13];
  const float* out_w1 = (const float*)d_in[14];
  const float* out_b1 = (const float*)d_in[15];
  const float* out_w2 = (const float*)d_in[16];
  const float* out_b2 = (const float*)d_in[17];
  float* out = (float*)d_out;

  const int* srcp = ei;
  const int* dstp = ei + NE;

  const int nodeBlocks = (NN + 255)/256;
  const int edgeBlocks = (NE + 255)/256;
  const int msgBlocks  = (NE + 255)/256;     // 256 edges per block
  const int scanBlocks = (NN + 1023)/1024;   // 98

  // ---- workspace layout (aligned to 256B) ----
  char* wp = (char*)d_ws;
  auto take = [&wp](size_t bytes) -> char* {
    char* r = wp;
    wp += (bytes + 255) & ~(size_t)255;
    return r;
  };
  float* h            = (float*)take((size_t)NN*H*sizeof(float));        // 25.6 MB
  unsigned short* P   = (unsigned short*)take((size_t)NN*128*sizeof(unsigned short)); // 25.6 MB
  float* tmp          = (float*)P;  // alias: disjoint lifetime with P
  float* agg          = (float*)take((size_t)NN*H*sizeof(float));        // 25.6 MB
  int* counts         = (int*)take((size_t)NN*sizeof(int));
  int* cursor         = (int*)take((size_t)NN*sizeof(int));
  int* row_excl       = (int*)take((size_t)NN*sizeof(int));
  int* part           = (int*)take(1024);
  int* ssrc           = (int*)take((size_t)NE*sizeof(int));
  int* sdst           = (int*)take((size_t)NE*sizeof(int));
  unsigned short* w2p = (unsigned short*)take((size_t)3*4096*sizeof(unsigned short));
  size_t need = (size_t)(wp - (char*)d_ws);

  if (ws_size >= need) {
    // ======== fast path: factored message MLP + MFMA + sorted segmented reduce ========
    hipMemsetAsync(counts, 0, NN*sizeof(int), stream);
    hipMemsetAsync(cursor, 0, NN*sizeof(int), stream);

    enc_a_kernel<<<nodeBlocks, 256, 0, stream>>>(x, enc_w1, enc_b1, tmp);
    mlp64_kernel<<<nodeBlocks, 256, 0, stream>>>(tmp, enc_w2, enc_b2, h);

    deg_kernel<<<edgeBlocks, 256, 0, stream>>>(dstp, counts);
    scan1_kernel<<<scanBlocks, 1024, 0, stream>>>(counts, row_excl, part);
    scan2_kernel<<<1, 128, 0, stream>>>(part, scanBlocks);
    fill_kernel<<<edgeBlocks, 256, 0, stream>>>(srcp, dstp, row_excl, part, cursor, ssrc, sdst);
    w2prep_kernel<<<(3*4096 + 255)/256, 256, 0, stream>>>(msg_w2, w2p);

    for (int l=0; l<3; l++){
      pproj_kernel<<<nodeBlocks, 256, 0, stream>>>(h, msg_w1 + (size_t)l*128*H,
                                                   msg_b1 + (size_t)l*H, P);
      hipMemsetAsync(agg, 0, (size_t)NN*H*sizeof(float), stream);
      msg_mfma_kernel<<<msgBlocks, 256, 0, stream>>>(P, w2p + (size_t)l*4096,
          msg_b2 + (size_t)l*H, ssrc, sdst, agg);
      upd_a_kernel<<<nodeBlocks, 256, 0, stream>>>(h, agg, counts,
          upd_w1 + (size_t)l*128*H, upd_b1 + (size_t)l*H, tmp);
      mlp64_kernel<<<nodeBlocks, 256, 0, stream>>>(tmp,
          upd_w2 + (size_t)l*H*H, upd_b2 + (size_t)l*H, h);
    }
    out_kernel2<<<nodeBlocks, 256, 0, stream>>>(h, out_w1, out_b1, out_w2, out_b2, out);
  } else {
    // ======== fallback: legacy atomic path (fits in ~52 MB) ========
    char* fp = (char*)d_ws;
    float* fh   = (float*)fp;  fp += (size_t)NN*H*sizeof(float);
    float* fagg = (float*)fp;  fp += (size_t)NN*H*sizeof(float);
    int* fcnt   = (int*)fp;

    hipMemsetAsync(fcnt, 0, NN*sizeof(int), stream);
    enc_kernel_legacy<<<nodeBlocks, 256, 0, stream>>>(x, enc_w1, enc_b1, enc_w2, enc_b2, fh);
    deg_kernel<<<edgeBlocks, 256, 0, stream>>>(dstp, fcnt);
    for (int l=0; l<3; l++){
      hipMemsetAsync(fagg, 0, (size_t)NN*H*sizeof(float), stream);
      msg_kernel_atomic<<<edgeBlocks, 256, 0, stream>>>(fh, srcp, dstp,
          msg_w1 + (size_t)l*128*H, msg_b1 + (size_t)l*H,
          msg_w2 + (size_t)l*H*H,   msg_b2 + (size_t)l*H, fagg);
      div_kernel<<<(NN*H/4 + 255)/256, 256, 0, stream>>>(fagg, fcnt);
      upd_kernel_legacy<<<nodeBlocks, 256, 0, stream>>>(fh, fagg,
          upd_w1 + (size_t)l*128*H, upd_b1 + (size_t)l*H,
          upd_w2 + (size_t)l*H*H,   upd_b2 + (size_t)l*H);
    }
    out_kernel2<<<nodeBlocks, 256, 0, stream>>>(fh, out_w1, out_b1, out_w2, out_b2, out);
  }
}

// Round 5
// 788.780 us; speedup vs baseline: 13.5091x; 1.7616x over previous
//
#include <hip/hip_runtime.h>
#include <math.h>

#define NN 100000
#define NE 1000000
#define H 64
#define MSTRIDE 258   // ushorts per channel row in msg LDS (256 edges + 2 pad)

typedef short bf16x8 __attribute__((ext_vector_type(8)));
typedef float f32x4  __attribute__((ext_vector_type(4)));

static __device__ __forceinline__ float relu_(float x){ return fmaxf(x, 0.0f); }

static __device__ __forceinline__ float b2f_(unsigned short u){
  union { float f; unsigned int i; } v; v.i = ((unsigned int)u) << 16; return v.f;
}
static __device__ __forceinline__ unsigned short f2b_(float f){
  union { float f; unsigned int i; } v; v.f = f;
  unsigned int r = (v.i + 0x7FFFu + ((v.i >> 16) & 1u)) >> 16;
  return (unsigned short)r;
}
static __device__ __forceinline__ unsigned int asu_(float f){
  union { float f; unsigned int i; } v; v.f = f; return v.i;
}
static __device__ __forceinline__ float asf_(unsigned int u){
  union { float f; unsigned int i; } v; v.i = u; return v.f;
}
static __device__ __forceinline__ unsigned int pk_(float lo, float hi){
  return (asu_(hi) & 0xffff0000u) | (asu_(lo) >> 16);
}
static __device__ __forceinline__ void fma32(float* o, float a, const float* wr){
  #pragma unroll
  for (int j=0;j<32;j++) o[j] = fmaf(a, wr[j], o[j]);
}

// ---------------- encoder stage A: t = relu(x@w1+b1), x:[N,5] ----------------
__global__ __launch_bounds__(256) void enc_a_kernel(
    const float* __restrict__ x,
    const float* __restrict__ w1, const float* __restrict__ b1,
    float* __restrict__ t)
{
  int v = blockIdx.x*256 + threadIdx.x;
  if (v >= NN) return;
  float in0[5];
  #pragma unroll
  for (int k=0;k<5;k++) in0[k] = x[(size_t)v*5 + k];
  #pragma unroll 1
  for (int half=0; half<2; half++){
    float o[32];
    #pragma unroll
    for (int j=0;j<32;j++) o[j] = b1[half*32 + j];
    #pragma unroll
    for (int k=0;k<5;k++) fma32(o, in0[k], w1 + k*H + half*32);
    float4* tw = (float4*)(t + (size_t)v*H + half*32);
    #pragma unroll
    for (int j4=0;j4<8;j4++){
      float4 q;
      q.x = relu_(o[4*j4+0]); q.y = relu_(o[4*j4+1]);
      q.z = relu_(o[4*j4+2]); q.w = relu_(o[4*j4+3]);
      tw[j4] = q;
    }
  }
}

// ---------------- encoder stage B: h(bf16) = relu(t@w2+b2) ----------------
__global__ __launch_bounds__(256) void mlp64b_kernel(
    const float* __restrict__ in,
    const float* __restrict__ w, const float* __restrict__ b,
    unsigned short* __restrict__ hbf)
{
  int v = blockIdx.x*256 + threadIdx.x;
  if (v >= NN) return;
  const float4* iv = (const float4*)(in + (size_t)v*H);
  #pragma unroll 1
  for (int half=0; half<2; half++){
    float o[32];
    #pragma unroll
    for (int j=0;j<32;j++) o[j] = b[half*32 + j];
    #pragma unroll 4
    for (int k4=0;k4<16;k4++){
      float4 a = iv[k4];
      const float* wr = w + (4*k4)*H + half*32;
      fma32(o, a.x, wr); fma32(o, a.y, wr+H); fma32(o, a.z, wr+2*H); fma32(o, a.w, wr+3*H);
    }
    unsigned int u[16];
    #pragma unroll
    for (int j=0;j<16;j++) u[j] = pk_(relu_(o[2*j]), relu_(o[2*j+1]));
    uint4* dp = (uint4*)(hbf + (size_t)v*H + half*32);
    #pragma unroll
    for (int j=0;j<4;j++) dp[j] = *(uint4*)&u[4*j];
  }
}

// ---------------- in-degree counts ----------------
__global__ __launch_bounds__(256) void deg_kernel(const int* __restrict__ dst,
                                                  int* __restrict__ counts)
{
  int e = blockIdx.x*256 + threadIdx.x;
  if (e < NE) atomicAdd(&counts[dst[e]], 1);
}

// ---------------- scan phase 1 ----------------
__global__ __launch_bounds__(1024) void scan1_kernel(const int* __restrict__ counts,
                                                     int* __restrict__ row_excl,
                                                     int* __restrict__ part)
{
  __shared__ int buf[1024];
  int tid = threadIdx.x;
  int i = blockIdx.x*1024 + tid;
  int v = (i < NN) ? counts[i] : 0;
  buf[tid] = v;
  __syncthreads();
  for (int off=1; off<1024; off<<=1){
    int t = (tid >= off) ? buf[tid-off] : 0;
    __syncthreads();
    buf[tid] += t;
    __syncthreads();
  }
  if (i < NN) row_excl[i] = buf[tid] - v;
  if (tid == 1023) part[blockIdx.x] = buf[1023];
}

// ---------------- scan phase 2 ----------------
__global__ __launch_bounds__(128) void scan2_kernel(int* __restrict__ part, int nparts)
{
  __shared__ int buf[128];
  int tid = threadIdx.x;
  int v = (tid < nparts) ? part[tid] : 0;
  buf[tid] = v;
  __syncthreads();
  for (int off=1; off<128; off<<=1){
    int t = (tid >= off) ? buf[tid-off] : 0;
    __syncthreads();
    buf[tid] += t;
    __syncthreads();
  }
  if (tid < nparts) part[tid] = buf[tid] - v;
}

// ---------------- fill dst-sorted src/dst arrays ----------------
__global__ __launch_bounds__(256) void fill_kernel(
    const int* __restrict__ src, const int* __restrict__ dst,
    const int* __restrict__ row_excl, const int* __restrict__ part,
    int* __restrict__ cursor, int* __restrict__ ssrc, int* __restrict__ sdst)
{
  int e = blockIdx.x*256 + threadIdx.x;
  if (e >= NE) return;
  int d = dst[e];
  int base = row_excl[d] + part[d >> 10];
  int p = base + atomicAdd(&cursor[d], 1);
  ssrc[p] = src[e];
  sdst[p] = d;
}

// ---------------- preswizzle ALL weights to bf16 MFMA B-fragment order ----------------
// frag index within a K x N weight: idx = ((kb*4+quad)*N + col)*8 + j,  k = kb*32+quad*8+j
// layout in wp (ushort elements):
//   [0,24576)        uw1p[l]  3 x 8192   (upd_w1[l], K=128,N=64)
//   [24576,36864)    uw2p[l]  3 x 4096   (upd_w2[l], K=64, N=64)
//   [36864,61440)    pprojp[l] 3 x 8192  (msg_w1[l] remapped: W'[k][p]=w1[(p>>6)*64+k][p&63], K=64,N=128)
//   [61440,65536)    ow1p     4096       (out_w1, K=64,N=64)
//   [65536,77824)    msgw2p[l] 3 x 4096  (msg_w2[l], K=64,N=64)
__global__ __launch_bounds__(256) void prep_all_kernel(
    const float* __restrict__ uw1, const float* __restrict__ uw2,
    const float* __restrict__ mw1, const float* __restrict__ mw2,
    const float* __restrict__ ow1, unsigned short* __restrict__ wp)
{
  int i = blockIdx.x*256 + threadIdx.x;
  if (i >= 77824) return;
  float val;
  if (i < 24576){
    int l = i / 8192, r = i & 8191;
    int j = r & 7, col = (r >> 3) & 63, g = r >> 9;
    int k = (g >> 2)*32 + (g & 3)*8 + j;
    val = uw1[(size_t)l*8192 + k*64 + col];
  } else if (i < 36864){
    int t = i - 24576; int l = t / 4096, r = t & 4095;
    int j = r & 7, col = (r >> 3) & 63, g = r >> 9;
    int k = (g >> 2)*32 + (g & 3)*8 + j;
    val = uw2[(size_t)l*4096 + k*64 + col];
  } else if (i < 61440){
    int t = i - 36864; int l = t / 8192, r = t & 8191;
    int j = r & 7, col = (r >> 3) & 127, g = r >> 10;
    int k = (g >> 2)*32 + (g & 3)*8 + j;
    val = mw1[(size_t)l*8192 + ((col >> 6)*64 + k)*64 + (col & 63)];
  } else if (i < 65536){
    int r = i - 61440;
    int j = r & 7, col = (r >> 3) & 63, g = r >> 9;
    int k = (g >> 2)*32 + (g & 3)*8 + j;
    val = ow1[k*64 + col];
  } else {
    int t = i - 65536; int l = t / 4096, r = t & 4095;
    int j = r & 7, col = (r >> 3) & 63, g = r >> 9;
    int k = (g >> 2)*32 + (g & 3)*8 + j;
    val = mw2[(size_t)l*4096 + k*64 + col];
  }
  wp[i] = f2b_(val);
}

// ---------------- MFMA message kernel (unchanged math, + XCD block swizzle) ----------
__global__ __launch_bounds__(256, 2) void msg_mfma_kernel(
    const unsigned short* __restrict__ P,
    const unsigned short* __restrict__ w2p,
    const float* __restrict__ b2,
    const int* __restrict__ ssrc, const int* __restrict__ sdst,
    float* __restrict__ agg)
{
  __shared__ unsigned short mlds[64*MSTRIDE];
  __shared__ int sloc[256], dloc[256];
  const int tid  = threadIdx.x;
  const int wave = tid >> 6, lane = tid & 63, quad = lane >> 4, c = lane & 15;

  // XCD-contiguous swizzle: blocks dispatched round-robin over 8 XCDs; map so each
  // XCD gets a contiguous range of sorted edges (agg/P2 slice fits its 4MB L2).
  int bid = blockIdx.x;
  int ng = gridDim.x >> 3;
  int lb = (bid < (ng << 3)) ? ((bid & 7)*ng + (bid >> 3)) : bid;

  int p = lb*256 + tid;
  int sv = 0, dv = -1;
  if (p < NE){ sv = ssrc[p]; dv = sdst[p]; }
  sloc[tid] = sv; dloc[tid] = dv;

  bf16x8 bfr[4][2];
  #pragma unroll
  for (int n=0;n<4;n++)
    #pragma unroll
    for (int kb=0;kb<2;kb++)
      bfr[n][kb] = *(const bf16x8*)(w2p + (((kb*4 + quad)*64 + n*16 + c) << 3));

  float bv[4];
  #pragma unroll
  for (int n=0;n<4;n++) bv[n] = b2[n*16 + c];

  __syncthreads();

  f32x4 acc[4][4];
  #pragma unroll
  for (int t=0;t<4;t++)
    #pragma unroll
    for (int n=0;n<4;n++)
      acc[t][n] = (f32x4){0.f, 0.f, 0.f, 0.f};

  const int ebase = wave*64;
  #pragma unroll 1
  for (int t=0;t<4;t++){
    int s = sloc[ebase + t*16 + c];
    int d = dloc[ebase + t*16 + c];
    if (d < 0) d = 0;
    const unsigned short* p1 = P + (size_t)s*128 + quad*8;
    const unsigned short* p2 = P + (size_t)d*128 + 64 + quad*8;
    bf16x8 af[2];
    #pragma unroll
    for (int kb=0;kb<2;kb++){
      uint4 u1 = *(const uint4*)(p1 + kb*32);
      uint4 u2 = *(const uint4*)(p2 + kb*32);
      unsigned int ua[4] = {u1.x, u1.y, u1.z, u1.w};
      unsigned int ub[4] = {u2.x, u2.y, u2.z, u2.w};
      union { unsigned int u[4]; bf16x8 v; } A;
      #pragma unroll
      for (int q2=0;q2<4;q2++){
        float lo = relu_(asf_(ua[q2] << 16)         + asf_(ub[q2] << 16));
        float hi = relu_(asf_(ua[q2] & 0xffff0000u) + asf_(ub[q2] & 0xffff0000u));
        A.u[q2] = pk_(lo, hi);
      }
      af[kb] = A.v;
    }
    #pragma unroll
    for (int n=0;n<4;n++){
      acc[t][n] = __builtin_amdgcn_mfma_f32_16x16x32_bf16(af[0], bfr[n][0], acc[t][n], 0, 0, 0);
      acc[t][n] = __builtin_amdgcn_mfma_f32_16x16x32_bf16(af[1], bfr[n][1], acc[t][n], 0, 0, 0);
    }
  }

  #pragma unroll
  for (int t=0;t<4;t++){
    int e0 = ebase + t*16 + quad*4;
    #pragma unroll
    for (int n=0;n<4;n++){
      int ch = n*16 + c;
      float v0 = relu_(acc[t][n][0] + bv[n]);
      float v1 = relu_(acc[t][n][1] + bv[n]);
      float v2 = relu_(acc[t][n][2] + bv[n]);
      float v3 = relu_(acc[t][n][3] + bv[n]);
      *(unsigned int*)&mlds[ch*MSTRIDE + e0]     = pk_(v0, v1);
      *(unsigned int*)&mlds[ch*MSTRIDE + e0 + 2] = pk_(v2, v3);
    }
  }
  __syncthreads();

  int ch = tid & 63;
  int cb = (tid >> 6) * 64;
  float s2 = 0.f; int cur = dloc[cb]; bool first = true;
  #pragma unroll 4
  for (int r=0;r<64;r++){
    int dr = dloc[cb + r];
    if (dr != cur){
      if (cur >= 0){
        if (first) atomicAdd(&agg[(size_t)cur*H + ch], s2);
        else       agg[(size_t)cur*H + ch] = s2;
      }
      first = false; s2 = 0.f; cur = dr;
    }
    s2 += b2f_(mlds[ch*MSTRIDE + cb + r]);
  }
  if (cur >= 0) atomicAdd(&agg[(size_t)cur*H + ch], s2);
}

// ---------------- fused node-side layer kernel (MFMA) ----------------
// mode 0 (l=0,1): h' = relu-MLP2([h||agg/deg]) -> hout(bf16) ; P_next = h'@W3 (+fold b3 on top half) -> Pout
// mode 1 (l=2):   h' as above; out = 2pi*sigmoid(relu(h'@ow1+b3)@ow2+ob2) -> outp
// mode 2 (pproj only): P = hbf@W3 (+fold b3) -> Pout     (GEMM1/2 skipped)
__global__ __launch_bounds__(256) void node_fused_kernel(
    const unsigned short* __restrict__ hbf,
    const float* __restrict__ agg, const int* __restrict__ counts,
    const unsigned short* __restrict__ uw1p, const float* __restrict__ ub1,
    const unsigned short* __restrict__ uw2p, const float* __restrict__ ub2,
    const unsigned short* __restrict__ w3p,  const float* __restrict__ b3,
    const float* __restrict__ ow2, const float* __restrict__ ob2,
    unsigned short* __restrict__ hout,
    unsigned short* __restrict__ Pout,
    float* __restrict__ outp,
    int mode)
{
  __shared__ __align__(16) unsigned short act[64*72];
  __shared__ __align__(16) unsigned short pst[64*136];
  const int tid = threadIdx.x, wave = tid >> 6, lane = tid & 63;
  const int quad = lane >> 4, c = lane & 15;
  const int vb = blockIdx.x*64;
  int myv = vb + wave*16 + c;
  int vld = myv < NN ? myv : NN-1;

  if (mode != 2){
    // ---- GEMM1: xin = [h || agg/deg], K=128 ----
    float invd = 1.0f / fmaxf((float)counts[vld], 1.0f);
    bf16x8 a1[4];
    a1[0] = *(const bf16x8*)(hbf + (size_t)vld*H + quad*8);
    a1[1] = *(const bf16x8*)(hbf + (size_t)vld*H + 32 + quad*8);
    #pragma unroll
    for (int kb2=0; kb2<2; kb2++){
      const float4* ap = (const float4*)(agg + (size_t)vld*H + kb2*32 + quad*8);
      float4 x0 = ap[0], x1 = ap[1];
      union { unsigned int u[4]; bf16x8 v; } A;
      A.u[0] = pk_(x0.x*invd, x0.y*invd);
      A.u[1] = pk_(x0.z*invd, x0.w*invd);
      A.u[2] = pk_(x1.x*invd, x1.y*invd);
      A.u[3] = pk_(x1.z*invd, x1.w*invd);
      a1[2+kb2] = A.v;
    }
    f32x4 acc1[4];
    #pragma unroll
    for (int n=0;n<4;n++) acc1[n] = (f32x4){0.f,0.f,0.f,0.f};
    #pragma unroll
    for (int n=0;n<4;n++){
      #pragma unroll
      for (int kb=0;kb<4;kb++){
        bf16x8 b = *(const bf16x8*)(uw1p + (((kb*4 + quad)*64 + n*16 + c) << 3));
        acc1[n] = __builtin_amdgcn_mfma_f32_16x16x32_bf16(a1[kb], b, acc1[n], 0, 0, 0);
      }
    }
    #pragma unroll
    for (int n=0;n<4;n++){
      float bb = ub1[n*16 + c];
      #pragma unroll
      for (int r=0;r<4;r++)
        act[(wave*16 + quad*4 + r)*72 + n*16 + c] = f2b_(relu_(acc1[n][r] + bb));
    }

    // ---- GEMM2: h' = relu(t@uw2+ub2), K=64 (A from act, same-wave LDS) ----
    bf16x8 a2[2];
    a2[0] = *(const bf16x8*)(act + (wave*16 + c)*72 + quad*8);
    a2[1] = *(const bf16x8*)(act + (wave*16 + c)*72 + 32 + quad*8);
    f32x4 acc2[4];
    #pragma unroll
    for (int n=0;n<4;n++) acc2[n] = (f32x4){0.f,0.f,0.f,0.f};
    #pragma unroll
    for (int n=0;n<4;n++){
      #pragma unroll
      for (int kb=0;kb<2;kb++){
        bf16x8 b = *(const bf16x8*)(uw2p + (((kb*4 + quad)*64 + n*16 + c) << 3));
        acc2[n] = __builtin_amdgcn_mfma_f32_16x16x32_bf16(a2[kb], b, acc2[n], 0, 0, 0);
      }
    }
    #pragma unroll
    for (int n=0;n<4;n++){
      float bb = ub2[n*16 + c];
      #pragma unroll
      for (int r=0;r<4;r++)
        act[(wave*16 + quad*4 + r)*72 + n*16 + c] = f2b_(relu_(acc2[n][r] + bb));
    }
  }

  // ---- GEMM3 A-frags ----
  bf16x8 a3[2];
  if (mode == 2){
    a3[0] = *(const bf16x8*)(hbf + (size_t)vld*H + quad*8);
    a3[1] = *(const bf16x8*)(hbf + (size_t)vld*H + 32 + quad*8);
  } else {
    a3[0] = *(const bf16x8*)(act + (wave*16 + c)*72 + quad*8);
    a3[1] = *(const bf16x8*)(act + (wave*16 + c)*72 + 32 + quad*8);
  }

  if (mode == 1){
    // out head GEMM: t2 = relu(h'@ow1 + b3), N=64
    f32x4 acc3[4];
    #pragma unroll
    for (int n=0;n<4;n++) acc3[n] = (f32x4){0.f,0.f,0.f,0.f};
    #pragma unroll
    for (int n=0;n<4;n++){
      #pragma unroll
      for (int kb=0;kb<2;kb++){
        bf16x8 b = *(const bf16x8*)(w3p + (((kb*4 + quad)*64 + n*16 + c) << 3));
        acc3[n] = __builtin_amdgcn_mfma_f32_16x16x32_bf16(a3[kb], b, acc3[n], 0, 0, 0);
      }
    }
    #pragma unroll
    for (int n=0;n<4;n++){
      float bb = b3[n*16 + c];
      #pragma unroll
      for (int r=0;r<4;r++)
        act[(wave*16 + quad*4 + r)*72 + n*16 + c] = f2b_(relu_(acc3[n][r] + bb));
    }
  } else {
    // P projection: N=128, fold b3 into top half (P2)
    f32x4 acc3[8];
    #pragma unroll
    for (int n=0;n<8;n++) acc3[n] = (f32x4){0.f,0.f,0.f,0.f};
    #pragma unroll
    for (int n=0;n<8;n++){
      #pragma unroll
      for (int kb=0;kb<2;kb++){
        bf16x8 b = *(const bf16x8*)(w3p + (((kb*4 + quad)*128 + n*16 + c) << 3));
        acc3[n] = __builtin_amdgcn_mfma_f32_16x16x32_bf16(a3[kb], b, acc3[n], 0, 0, 0);
      }
    }
    #pragma unroll
    for (int n=0;n<8;n++){
      int ch = n*16 + c;
      float bb = (ch >= 64) ? b3[ch - 64] : 0.0f;
      #pragma unroll
      for (int r=0;r<4;r++)
        pst[(wave*16 + quad*4 + r)*136 + ch] = f2b_(acc3[n][r] + bb);
    }
  }

  __syncthreads();

  if (mode == 0){
    // coalesced h' store (bf16)
    #pragma unroll
    for (int rr=0; rr<2; rr++){
      int idx = tid + rr*256;            // 512 uint4 = 64x64 ushort
      int node = idx >> 3, ko = (idx & 7)*8;
      int v = vb + node;
      if (v < NN) *(uint4*)(hout + (size_t)v*H + ko) = *(const uint4*)(act + node*72 + ko);
    }
  }
  if (mode == 0 || mode == 2){
    // coalesced P store (bf16)
    #pragma unroll
    for (int rr=0; rr<4; rr++){
      int idx = tid + rr*256;            // 1024 uint4 = 64x128 ushort
      int node = idx >> 4, cho = (idx & 15)*8;
      int v = vb + node;
      if (v < NN) *(uint4*)(Pout + (size_t)v*128 + cho) = *(const uint4*)(pst + node*136 + cho);
    }
  }
  if (mode == 1){
    if (tid < 192){
      int node = tid / 3;
      int v = vb + node;
      if (v < NN){
        int cm = tid - node*3;
        float s = ob2[cm];
        #pragma unroll 8
        for (int k=0;k<64;k++)
          s = fmaf(b2f_(act[node*72 + k]), ow2[k*3 + cm], s);
        outp[(size_t)v*3 + cm] = 6.283185307179586f / (1.0f + __expf(-s));
      }
    }
  }
}

// ================= legacy fallback kernels (known correct; small ws) =================
__global__ __launch_bounds__(256) void enc_kernel_legacy(
    const float* __restrict__ x,
    const float* __restrict__ w1, const float* __restrict__ b1,
    const float* __restrict__ w2, const float* __restrict__ b2,
    float* __restrict__ h)
{
  int v = blockIdx.x*256 + threadIdx.x;
  if (v >= NN) return;
  float in0[5];
  #pragma unroll
  for (int k=0;k<5;k++) in0[k] = x[v*5+k];
  float hid[H];
  #pragma unroll
  for (int j=0;j<H;j++) hid[j] = b1[j];
  #pragma unroll
  for (int k=0;k<5;k++){
    #pragma unroll
    for (int j=0;j<H;j++) hid[j] = fmaf(in0[k], w1[k*H+j], hid[j]);
  }
  float o[H];
  #pragma unroll
  for (int j=0;j<H;j++) o[j] = b2[j];
  #pragma unroll
  for (int k=0;k<H;k++){
    float hk = relu_(hid[k]);
    #pragma unroll
    for (int j=0;j<H;j++) o[j] = fmaf(hk, w2[k*H+j], o[j]);
  }
  float4* hw = (float4*)(h + (size_t)v*H);
  #pragma unroll
  for (int j4=0;j4<H/4;j4++){
    float4 t;
    t.x = relu_(o[4*j4+0]); t.y = relu_(o[4*j4+1]);
    t.z = relu_(o[4*j4+2]); t.w = relu_(o[4*j4+3]);
    hw[j4] = t;
  }
}

__global__ __launch_bounds__(256) void msg_kernel_atomic(
    const float* __restrict__ h,
    const int* __restrict__ src, const int* __restrict__ dst,
    const float* __restrict__ w1, const float* __restrict__ b1,
    const float* __restrict__ w2, const float* __restrict__ b2,
    float* __restrict__ agg)
{
  int e = blockIdx.x*256 + threadIdx.x;
  if (e >= NE) return;
  int s = src[e], d = dst[e];
  const float4* hs = (const float4*)(h + (size_t)s*H);
  const float4* hd = (const float4*)(h + (size_t)d*H);
  float hid[H];
  #pragma unroll
  for (int j=0;j<H;j++) hid[j] = b1[j];
  #pragma unroll 4
  for (int k4=0;k4<16;k4++){
    float4 a = hs[k4];
    const float* wr = w1 + (size_t)(4*k4)*H;
    #pragma unroll
    for (int j=0;j<H;j++) hid[j] = fmaf(a.x, wr[j], hid[j]);
    #pragma unroll
    for (int j=0;j<H;j++) hid[j] = fmaf(a.y, wr[H+j], hid[j]);
    #pragma unroll
    for (int j=0;j<H;j++) hid[j] = fmaf(a.z, wr[2*H+j], hid[j]);
    #pragma unroll
    for (int j=0;j<H;j++) hid[j] = fmaf(a.w, wr[3*H+j], hid[j]);
  }
  #pragma unroll 4
  for (int k4=0;k4<16;k4++){
    float4 a = hd[k4];
    const float* wr = w1 + (size_t)(64 + 4*k4)*H;
    #pragma unroll
    for (int j=0;j<H;j++) hid[j] = fmaf(a.x, wr[j], hid[j]);
    #pragma unroll
    for (int j=0;j<H;j++) hid[j] = fmaf(a.y, wr[H+j], hid[j]);
    #pragma unroll
    for (int j=0;j<H;j++) hid[j] = fmaf(a.z, wr[2*H+j], hid[j]);
    #pragma unroll
    for (int j=0;j<H;j++) hid[j] = fmaf(a.w, wr[3*H+j], hid[j]);
  }
  float o[H];
  #pragma unroll
  for (int j=0;j<H;j++) o[j] = b2[j];
  #pragma unroll
  for (int k=0;k<H;k++){
    float hk = relu_(hid[k]);
    #pragma unroll
    for (int j=0;j<H;j++) o[j] = fmaf(hk, w2[k*H+j], o[j]);
  }
  float* arow = agg + (size_t)d*H;
  #pragma unroll
  for (int j=0;j<H;j++) atomicAdd(arow + j, relu_(o[j]));
}

__global__ __launch_bounds__(256) void div_kernel(float* __restrict__ agg,
                                                  const int* __restrict__ counts)
{
  int i = blockIdx.x*256 + threadIdx.x;
  if (i >= NN*H/4) return;
  int v = i / (H/4);
  float invd = 1.0f / fmaxf((float)counts[v], 1.0f);
  float4* a = (float4*)agg + i;
  float4 t = *a;
  t.x *= invd; t.y *= invd; t.z *= invd; t.w *= invd;
  *a = t;
}

__global__ __launch_bounds__(256) void upd_kernel_legacy(
    float* __restrict__ h, const float* __restrict__ agg,
    const float* __restrict__ w1, const float* __restrict__ b1,
    const float* __restrict__ w2, const float* __restrict__ b2)
{
  int v = blockIdx.x*256 + threadIdx.x;
  if (v >= NN) return;
  const float4* hv = (const float4*)(h + (size_t)v*H);
  const float4* av = (const float4*)(agg + (size_t)v*H);
  float hid[H];
  #pragma unroll
  for (int j=0;j<H;j++) hid[j] = b1[j];
  #pragma unroll 4
  for (int k4=0;k4<16;k4++){
    float4 a = hv[k4];
    const float* wr = w1 + (size_t)(4*k4)*H;
    #pragma unroll
    for (int j=0;j<H;j++) hid[j] = fmaf(a.x, wr[j], hid[j]);
    #pragma unroll
    for (int j=0;j<H;j++) hid[j] = fmaf(a.y, wr[H+j], hid[j]);
    #pragma unroll
    for (int j=0;j<H;j++) hid[j] = fmaf(a.z, wr[2*H+j], hid[j]);
    #pragma unroll
    for (int j=0;j<H;j++) hid[j] = fmaf(a.w, wr[3*H+j], hid[j]);
  }
  #pragma unroll 4
  for (int k4=0;k4<16;k4++){
    float4 a = av[k4];
    const float* wr = w1 + (size_t)(64 + 4*k4)*H;
    #pragma unroll
    for (int j=0;j<H;j++) hid[j] = fmaf(a.x, wr[j], hid[j]);
    #pragma unroll
    for (int j=0;j<H;j++) hid[j] = fmaf(a.y, wr[H+j], hid[j]);
    #pragma unroll
    for (int j=0;j<H;j++) hid[j] = fmaf(a.z, wr[2*H+j], hid[j]);
    #pragma unroll
    for (int j=0;j<H;j++) hid[j] = fmaf(a.w, wr[3*H+j], hid[j]);
  }
  float o[H];
  #pragma unroll
  for (int j=0;j<H;j++) o[j] = b2[j];
  #pragma unroll
  for (int k=0;k<H;k++){
    float hk = relu_(hid[k]);
    #pragma unroll
    for (int j=0;j<H;j++) o[j] = fmaf(hk, w2[k*H+j], o[j]);
  }
  float4* hw = (float4*)(h + (size_t)v*H);
  #pragma unroll
  for (int j4=0;j4<H/4;j4++){
    float4 t;
    t.x = relu_(o[4*j4+0]); t.y = relu_(o[4*j4+1]);
    t.z = relu_(o[4*j4+2]); t.w = relu_(o[4*j4+3]);
    hw[j4] = t;
  }
}

__global__ __launch_bounds__(256) void out_kernel2(
    const float* __restrict__ h,
    const float* __restrict__ w1, const float* __restrict__ b1,
    const float* __restrict__ w2, const float* __restrict__ b2,
    float* __restrict__ out)
{
  int v = blockIdx.x*256 + threadIdx.x;
  if (v >= NN) return;
  const float4* hv = (const float4*)(h + (size_t)v*H);
  float pr[3] = { b2[0], b2[1], b2[2] };
  #pragma unroll 1
  for (int half=0; half<2; half++){
    float o[32];
    #pragma unroll
    for (int j=0;j<32;j++) o[j] = b1[half*32 + j];
    #pragma unroll 4
    for (int k4=0;k4<16;k4++){
      float4 a = hv[k4];
      const float* wr = w1 + (4*k4)*H + half*32;
      fma32(o, a.x, wr); fma32(o, a.y, wr+H); fma32(o, a.z, wr+2*H); fma32(o, a.w, wr+3*H);
    }
    #pragma unroll
    for (int j=0;j<32;j++){
      float hk = relu_(o[j]);
      int k = half*32 + j;
      pr[0] = fmaf(hk, w2[k*3+0], pr[0]);
      pr[1] = fmaf(hk, w2[k*3+1], pr[1]);
      pr[2] = fmaf(hk, w2[k*3+2], pr[2]);
    }
  }
  #pragma unroll
  for (int c=0;c<3;c++)
    out[(size_t)v*3 + c] = 6.283185307179586f / (1.0f + __expf(-pr[c]));
}

// =====================================================================

extern "C" void kernel_launch(void* const* d_in, const int* in_sizes, int n_in,
                              void* d_out, int out_size, void* d_ws, size_t ws_size,
                              hipStream_t stream)
{
  const float* x      = (const float*)d_in[0];
  const int*   ei     = (const int*)  d_in[1];
  const float* enc_w1 = (const float*)d_in[2];
  const float* enc_b1 = (const float*)d_in[3];
  const float* enc_w2 = (const float*)d_in[4];
  const float* enc_b2 = (const float*)d_in[5];
  const float* msg_w1 = (const float*)d_in[6];
  const float* msg_b1 = (const float*)d_in[7];
  const float* msg_w2 = (const float*)d_in[8];
  const float* msg_b2 = (const float*)d_in[9];
  const float* upd_w1 = (const float*)d_in[10];
  const float* upd_b1 = (const float*)d_in[11];
  const float* upd_w2 = (const float*)d_in[12];
  const float* upd_b2 = (const float*)d_in[13];
  const float* out_w1 = (const float*)d_in[14];
  const float* out_b1 = (const float*)d_in[15];
  const float* out_w2 = (const float*)d_in[16];
  const float* out_b2 = (const float*)d_in[17];
  float* out = (float*)d_out;

  const int* srcp = ei;
  const int* dstp = ei + NE;

  const int nodeBlocks  = (NN + 255)/256;
  const int edgeBlocks  = (NE + 255)/256;
  const int msgBlocks   = (NE + 255)/256;
  const int scanBlocks  = (NN + 1023)/1024;
  const int fusedBlocks = (NN + 63)/64;       // 1563

  // ---- workspace layout ----
  char* wp_ = (char*)d_ws;
  auto take = [&wp_](size_t bytes) -> char* {
    char* r = wp_;
    wp_ += (bytes + 255) & ~(size_t)255;
    return r;
  };
  unsigned short* hbf = (unsigned short*)take((size_t)NN*H*sizeof(unsigned short)); // 12.8 MB
  unsigned short* P   = (unsigned short*)take((size_t)NN*128*sizeof(unsigned short)); // 25.6 MB
  float* tmp          = (float*)P;  // fp32 NN*64 aliases P; disjoint lifetime
  float* agg          = (float*)take((size_t)NN*H*sizeof(float));                  // 25.6 MB
  int* counts         = (int*)take((size_t)NN*sizeof(int));
  int* cursor         = (int*)take((size_t)NN*sizeof(int));
  int* row_excl       = (int*)take((size_t)NN*sizeof(int));
  int* part           = (int*)take(1024);
  int* ssrc           = (int*)take((size_t)NE*sizeof(int));
  int* sdst           = (int*)take((size_t)NE*sizeof(int));
  unsigned short* wpz = (unsigned short*)take((size_t)77824*sizeof(unsigned short));
  size_t need = (size_t)(wp_ - (char*)d_ws);

  // preswizzled-weight offsets (ushort elements)
  const size_t UW1 = 0, UW2 = 24576, PPJ = 36864, OW1 = 61440, MW2 = 65536;

  if (ws_size >= need) {
    hipMemsetAsync(counts, 0, NN*sizeof(int), stream);
    hipMemsetAsync(cursor, 0, NN*sizeof(int), stream);

    enc_a_kernel<<<nodeBlocks, 256, 0, stream>>>(x, enc_w1, enc_b1, tmp);
    mlp64b_kernel<<<nodeBlocks, 256, 0, stream>>>(tmp, enc_w2, enc_b2, hbf);

    deg_kernel<<<edgeBlocks, 256, 0, stream>>>(dstp, counts);
    scan1_kernel<<<scanBlocks, 1024, 0, stream>>>(counts, row_excl, part);
    scan2_kernel<<<1, 128, 0, stream>>>(part, scanBlocks);
    fill_kernel<<<edgeBlocks, 256, 0, stream>>>(srcp, dstp, row_excl, part, cursor, ssrc, sdst);
    prep_all_kernel<<<(77824 + 255)/256, 256, 0, stream>>>(upd_w1, upd_w2, msg_w1, msg_w2, out_w1, wpz);

    // layer-0 P projection (mode 2)
    node_fused_kernel<<<fusedBlocks, 256, 0, stream>>>(
        hbf, agg, counts,
        nullptr, nullptr, nullptr, nullptr,
        wpz + PPJ, msg_b1, nullptr, nullptr,
        nullptr, P, nullptr, 2);

    for (int l=0; l<3; l++){
      hipMemsetAsync(agg, 0, (size_t)NN*H*sizeof(float), stream);
      msg_mfma_kernel<<<msgBlocks, 256, 0, stream>>>(P, wpz + MW2 + (size_t)l*4096,
          msg_b2 + (size_t)l*H, ssrc, sdst, agg);
      if (l < 2){
        node_fused_kernel<<<fusedBlocks, 256, 0, stream>>>(
            hbf, agg, counts,
            wpz + UW1 + (size_t)l*8192, upd_b1 + (size_t)l*H,
            wpz + UW2 + (size_t)l*4096, upd_b2 + (size_t)l*H,
            wpz + PPJ + (size_t)(l+1)*8192, msg_b1 + (size_t)(l+1)*H,
            nullptr, nullptr,
            hbf, P, nullptr, 0);
      } else {
        node_fused_kernel<<<fusedBlocks, 256, 0, stream>>>(
            hbf, agg, counts,
            wpz + UW1 + (size_t)l*8192, upd_b1 + (size_t)l*H,
            wpz + UW2 + (size_t)l*4096, upd_b2 + (size_t)l*H,
            wpz + OW1, out_b1,
            out_w2, out_b2,
            nullptr, nullptr, out, 1);
      }
    }
  } else {
    // ======== fallback: legacy atomic path (fits in ~52 MB) ========
    char* fp = (char*)d_ws;
    float* fh   = (float*)fp;  fp += (size_t)NN*H*sizeof(float);
    float* fagg = (float*)fp;  fp += (size_t)NN*H*sizeof(float);
    int* fcnt   = (int*)fp;

    hipMemsetAsync(fcnt, 0, NN*sizeof(int), stream);
    enc_kernel_legacy<<<nodeBlocks, 256, 0, stream>>>(x, enc_w1, enc_b1, enc_w2, enc_b2, fh);
    deg_kernel<<<edgeBlocks, 256, 0, stream>>>(dstp, fcnt);
    for (int l=0; l<3; l++){
      hipMemsetAsync(fagg, 0, (size_t)NN*H*sizeof(float), stream);
      msg_kernel_atomic<<<edgeBlocks, 256, 0, stream>>>(fh, srcp, dstp,
          msg_w1 + (size_t)l*128*H, msg_b1 + (size_t)l*H,
          msg_w2 + (size_t)l*H*H,   msg_b2 + (size_t)l*H, fagg);
      div_kernel<<<(NN*H/4 + 255)/256, 256, 0, stream>>>(fagg, fcnt);
      upd_kernel_legacy<<<nodeBlocks, 256, 0, stream>>>(fh, fagg,
          upd_w1 + (size_t)l*128*H, upd_b1 + (size_t)l*H,
          upd_w2 + (size_t)l*H*H,   upd_b2 + (size_t)l*H);
    }
    out_kernel2<<<nodeBlocks, 256, 0, stream>>>(fh, out_w1, out_b1, out_w2, out_b2, out);
  }
}